// Round 1
// baseline (574.342 us; speedup 1.0000x reference)
//
#include <hip/hip_runtime.h>
#include <hip/hip_bf16.h>

typedef unsigned short u16;
typedef __attribute__((ext_vector_type(8))) __bf16 bf16x8;
typedef __attribute__((ext_vector_type(4))) float f32x4;
typedef __attribute__((ext_vector_type(8))) unsigned short ushort8v;
typedef __attribute__((ext_vector_type(4))) unsigned short u16x4;

#define DEV __device__ __forceinline__

DEV u16 f2bf(float f) {
    union { float f; unsigned int i; } u; u.f = f;
    unsigned int x = u.i;
    unsigned int r = (x + 0x7fffu + ((x >> 16) & 1u)) >> 16;
    return (u16)r;
}
DEV float bf2f(u16 h) {
    union { unsigned int i; float f; } u; u.i = ((unsigned int)h) << 16;
    return u.f;
}

// ---------------------------------------------------------------------------
// Weight conversion: pack [Wq;Wk;Wv] as [3072,1024] bf16, then W1, W2.
// ---------------------------------------------------------------------------
__global__ __launch_bounds__(256) void cvt_w(
    const float* __restrict__ wq, const float* __restrict__ wk,
    const float* __restrict__ wv, const float* __restrict__ w1,
    const float* __restrict__ w2, u16* __restrict__ dst)
{
    const int i = (blockIdx.x * 256 + threadIdx.x) * 4;
    if (i >= (1 << 20)) return;
    auto conv4 = [](float4 a) {
        u16x4 r; r[0] = f2bf(a.x); r[1] = f2bf(a.y); r[2] = f2bf(a.z); r[3] = f2bf(a.w);
        return r;
    };
    *(u16x4*)(dst + i)               = conv4(*(const float4*)(wq + i));
    *(u16x4*)(dst + (1 << 20) + i)   = conv4(*(const float4*)(wk + i));
    *(u16x4*)(dst + (2 << 20) + i)   = conv4(*(const float4*)(wv + i));
    *(u16x4*)(dst + (3 << 20) + i)   = conv4(*(const float4*)(w1 + i));
    *(u16x4*)(dst + (4 << 20) + i)   = conv4(*(const float4*)(w2 + i));
}

// ---------------------------------------------------------------------------
// Fused (optional residual-add) + LayerNorm. Row per block (1024 cols).
// If ADD: xt_out = xin + bf16(addbf) stored fp32; LN applied to sum.
// y_bf gets bf16 of the normalized row.
// ---------------------------------------------------------------------------
template<bool ADD>
__global__ __launch_bounds__(256) void ln_kernel(
    const float* __restrict__ xin, const u16* __restrict__ addbf,
    const float* __restrict__ g, const float* __restrict__ be,
    float* __restrict__ xt_out, u16* __restrict__ y_bf)
{
    const int row = blockIdx.x;
    const int tid = threadIdx.x;
    const size_t base = (size_t)row * 1024 + tid * 4;

    float4 xv = *(const float4*)(xin + base);
    float v[4] = {xv.x, xv.y, xv.z, xv.w};
    if (ADD) {
        u16x4 a = *(const u16x4*)(addbf + base);
        v[0] += bf2f(a[0]); v[1] += bf2f(a[1]); v[2] += bf2f(a[2]); v[3] += bf2f(a[3]);
        float4 o; o.x = v[0]; o.y = v[1]; o.z = v[2]; o.w = v[3];
        *(float4*)(xt_out + base) = o;
    }
    float s = 0.f, ss = 0.f;
    #pragma unroll
    for (int j = 0; j < 4; ++j) { s += v[j]; ss += v[j] * v[j]; }
    #pragma unroll
    for (int o = 32; o > 0; o >>= 1) { s += __shfl_xor(s, o); ss += __shfl_xor(ss, o); }
    __shared__ float red[8];
    const int w = tid >> 6;
    if ((tid & 63) == 0) { red[w * 2] = s; red[w * 2 + 1] = ss; }
    __syncthreads();
    s  = red[0] + red[2] + red[4] + red[6];
    ss = red[1] + red[3] + red[5] + red[7];
    const float mu = s * (1.0f / 1024.0f);
    const float var = ss * (1.0f / 1024.0f) - mu * mu;
    const float rstd = rsqrtf(var + 1e-5f);

    const int col = tid * 4;
    float4 gv = *(const float4*)(g + col);
    float4 bv = *(const float4*)(be + col);
    u16x4 o4;
    o4[0] = f2bf((v[0] - mu) * rstd * gv.x + bv.x);
    o4[1] = f2bf((v[1] - mu) * rstd * gv.y + bv.y);
    o4[2] = f2bf((v[2] - mu) * rstd * gv.z + bv.z);
    o4[3] = f2bf((v[3] - mu) * rstd * gv.w + bv.w);
    *(u16x4*)(y_bf + base) = o4;
}

// ---------------------------------------------------------------------------
// GEMM: C[M,N] = A[M,K] @ Bt[N,K]^T   (A, Bt bf16 row-major)
// 128x128 tile, BK=32, 4 waves (2x2), 4x4 16x16 frags per wave (m97 shape).
// EPI 0: store bf16. 1: +bias, relu, bf16. 2: +bias +resid, fp32.
// ---------------------------------------------------------------------------
template<int EPI>
__global__ __launch_bounds__(256, 2) void gemm_bt(
    const u16* __restrict__ A, const u16* __restrict__ Bt,
    void* __restrict__ Cout, const float* __restrict__ bias,
    const float* __restrict__ resid, int M, int N, int K)
{
    __shared__ u16 As[128 * 32];
    __shared__ u16 Bs[128 * 32];
    const int tid = threadIdx.x;
    const int l = tid & 63;
    const int w = tid >> 6;
    const int wm = w >> 1, wn = w & 1;
    const int fr = l & 15, fc = l >> 4;
    const size_t rowA0 = (size_t)blockIdx.x * 128;
    const size_t rowB0 = (size_t)blockIdx.y * 128;

    f32x4 acc[4][4] = {};
    const int ldoff = fr * 32 + fc * 8;

    const int nkt = K >> 5;
    for (int kt = 0; kt < nkt; ++kt) {
        __syncthreads();
        const int k0 = kt << 5;
        #pragma unroll
        for (int p = 0; p < 2; ++p) {
            const int rr = p * 64 + w * 16 + (l >> 2);
            const int cc = (l & 3) * 8;
            const u16* ga = A  + (rowA0 + rr) * K + k0 + cc;
            const u16* gb = Bt + (rowB0 + rr) * K + k0 + cc;
            __builtin_amdgcn_global_load_lds(
                (const __attribute__((address_space(1))) void*)ga,
                (__attribute__((address_space(3))) void*)(As + (p * 64 + w * 16) * 32),
                16, 0, 0);
            __builtin_amdgcn_global_load_lds(
                (const __attribute__((address_space(1))) void*)gb,
                (__attribute__((address_space(3))) void*)(Bs + (p * 64 + w * 16) * 32),
                16, 0, 0);
        }
        __syncthreads();
        bf16x8 af[4], bfv[4];
        #pragma unroll
        for (int m = 0; m < 4; ++m)
            af[m] = *(const bf16x8*)(As + (wm * 64 + m * 16) * 32 + ldoff);
        #pragma unroll
        for (int n = 0; n < 4; ++n)
            bfv[n] = *(const bf16x8*)(Bs + (wn * 64 + n * 16) * 32 + ldoff);
        #pragma unroll
        for (int m = 0; m < 4; ++m)
            #pragma unroll
            for (int n = 0; n < 4; ++n)
                acc[m][n] = __builtin_amdgcn_mfma_f32_16x16x32_bf16(
                    af[m], bfv[n], acc[m][n], 0, 0, 0);
    }

    const int r0 = (int)rowA0 + wm * 64;
    const int c0 = (int)rowB0 + wn * 64;
    #pragma unroll
    for (int m = 0; m < 4; ++m) {
        #pragma unroll
        for (int n = 0; n < 4; ++n) {
            const int row = r0 + m * 16 + fc * 4;
            const int col = c0 + n * 16 + fr;
            #pragma unroll
            for (int j = 0; j < 4; ++j) {
                float v = acc[m][n][j];
                const size_t idx = (size_t)(row + j) * N + col;
                if constexpr (EPI == 0) {
                    ((u16*)Cout)[idx] = f2bf(v);
                } else if constexpr (EPI == 1) {
                    v += bias[col];
                    v = fmaxf(v, 0.0f);
                    ((u16*)Cout)[idx] = f2bf(v);
                } else {
                    v += bias[col] + resid[idx];
                    ((float*)Cout)[idx] = v;
                }
            }
        }
    }
}

// ---------------------------------------------------------------------------
// Causal flash attention. qkv: [B,S,3072] bf16 (Q|K|V per 1024 block,
// head h at h*64). Block = (qt, h, b): 64 q-rows, 4 waves x 16 rows.
// KV tiles of 32. Online softmax fp32. Out: bf16 [B,S,1024].
// ---------------------------------------------------------------------------
__global__ __launch_bounds__(256, 2) void attn_fwd(
    const u16* __restrict__ qkv, u16* __restrict__ attout)
{
    __shared__ u16 Ks[32 * 64];
    __shared__ u16 Vt[64 * 32];
    __shared__ u16 Pw[4][16 * 32];

    const int qt = blockIdx.x, h = blockIdx.y, b = blockIdx.z;
    const int tid = threadIdx.x, l = tid & 63, w = tid >> 6;
    const int fr = l & 15, fc = l >> 4;
    const size_t bS = (size_t)b * 2048;
    const int qbase = qt * 64 + w * 16;

    const u16* qp = qkv + (bS + qbase + fr) * 3072 + h * 64 + fc * 8;
    const bf16x8 qf0 = *(const bf16x8*)qp;
    const bf16x8 qf1 = *(const bf16x8*)(qp + 32);

    f32x4 acc_o[4] = {};
    float m_run[4], l_run[4];
    #pragma unroll
    for (int j = 0; j < 4; ++j) { m_run[j] = -__builtin_inff(); l_run[j] = 0.0f; }

    const int nkt = (qt + 1) * 2;
    for (int kt = 0; kt < nkt; ++kt) {
        __syncthreads();
        {   // stage K[32][64] (linear) via global_load_lds
            const int rr = w * 8 + (l >> 3);
            const int cc = (l & 7) * 8;
            const u16* gk = qkv + (bS + kt * 32 + rr) * 3072 + 1024 + h * 64 + cc;
            __builtin_amdgcn_global_load_lds(
                (const __attribute__((address_space(1))) void*)gk,
                (__attribute__((address_space(3))) void*)(Ks + w * 512),
                16, 0, 0);
        }
        {   // stage V transposed: Vt[d][kv]
            const int kv = tid >> 3;
            const int d0 = (tid & 7) * 8;
            const u16* gv = qkv + (bS + kt * 32 + kv) * 3072 + 2048 + h * 64 + d0;
            ushort8v vv = *(const ushort8v*)gv;
            #pragma unroll
            for (int j = 0; j < 8; ++j)
                Vt[(d0 + j) * 32 + kv] = vv[j];
        }
        __syncthreads();

        // S = Q K^T (16q x 32kv)
        f32x4 sa[2] = {};
        #pragma unroll
        for (int nb = 0; nb < 2; ++nb) {
            const u16* kb = Ks + (nb * 16 + fr) * 64 + fc * 8;
            sa[nb] = __builtin_amdgcn_mfma_f32_16x16x32_bf16(
                qf0, *(const bf16x8*)kb, sa[nb], 0, 0, 0);
            sa[nb] = __builtin_amdgcn_mfma_f32_16x16x32_bf16(
                qf1, *(const bf16x8*)(kb + 32), sa[nb], 0, 0, 0);
        }

        float p[2][4], mx[4];
        #pragma unroll
        for (int j = 0; j < 4; ++j) {
            const int qg = qbase + fc * 4 + j;
            const int kg = kt * 32 + fr;
            const float s0 = (kg      <= qg) ? sa[0][j] * 0.125f : -__builtin_inff();
            const float s1 = (kg + 16 <= qg) ? sa[1][j] * 0.125f : -__builtin_inff();
            p[0][j] = s0; p[1][j] = s1;
            mx[j] = fmaxf(s0, s1);
        }
        #pragma unroll
        for (int o = 1; o < 16; o <<= 1)
            #pragma unroll
            for (int j = 0; j < 4; ++j)
                mx[j] = fmaxf(mx[j], __shfl_xor(mx[j], o));

        float alpha[4], rs[4];
        #pragma unroll
        for (int j = 0; j < 4; ++j) {
            const float mn = fmaxf(m_run[j], mx[j]);
            alpha[j] = __expf(m_run[j] - mn);
            m_run[j] = mn;
            p[0][j] = __expf(p[0][j] - mn);
            p[1][j] = __expf(p[1][j] - mn);
            rs[j] = p[0][j] + p[1][j];
        }
        #pragma unroll
        for (int o = 1; o < 16; o <<= 1)
            #pragma unroll
            for (int j = 0; j < 4; ++j)
                rs[j] += __shfl_xor(rs[j], o);
        #pragma unroll
        for (int j = 0; j < 4; ++j)
            l_run[j] = l_run[j] * alpha[j] + rs[j];
        #pragma unroll
        for (int d = 0; d < 4; ++d)
            #pragma unroll
            for (int j = 0; j < 4; ++j)
                acc_o[d][j] *= alpha[j];

        // P -> LDS (per-wave buffer), then PV
        u16* pw = &Pw[w][0];
        #pragma unroll
        for (int j = 0; j < 4; ++j) {
            pw[(fc * 4 + j) * 32 + fr]      = f2bf(p[0][j]);
            pw[(fc * 4 + j) * 32 + 16 + fr] = f2bf(p[1][j]);
        }
        __syncthreads();
        const bf16x8 pf = *(const bf16x8*)(pw + fr * 32 + fc * 8);
        #pragma unroll
        for (int d = 0; d < 4; ++d) {
            const bf16x8 vf = *(const bf16x8*)(Vt + (d * 16 + fr) * 32 + fc * 8);
            acc_o[d] = __builtin_amdgcn_mfma_f32_16x16x32_bf16(pf, vf, acc_o[d], 0, 0, 0);
        }
    }

    #pragma unroll
    for (int d = 0; d < 4; ++d)
        #pragma unroll
        for (int j = 0; j < 4; ++j)
            attout[(bS + qbase + fc * 4 + j) * 1024 + h * 64 + d * 16 + fr] =
                f2bf(acc_o[d][j] / l_run[j]);
}

// ---------------------------------------------------------------------------
extern "C" void kernel_launch(void* const* d_in, const int* in_sizes, int n_in,
                              void* d_out, int out_size, void* d_ws, size_t ws_size,
                              hipStream_t stream)
{
    const float* x    = (const float*)d_in[0];
    const float* Wq   = (const float*)d_in[1];
    const float* Wk   = (const float*)d_in[2];
    const float* Wv   = (const float*)d_in[3];
    const float* ln1g = (const float*)d_in[4];
    const float* ln1b = (const float*)d_in[5];
    const float* ln2g = (const float*)d_in[6];
    const float* ln2b = (const float*)d_in[7];
    const float* W1   = (const float*)d_in[8];
    const float* b1   = (const float*)d_in[9];
    const float* W2   = (const float*)d_in[10];
    const float* b2   = (const float*)d_in[11];

    char* ws = (char*)d_ws;
    u16*   wbf  = (u16*)(ws);                        // 5M bf16 = 10 MB
    u16*   xn   = (u16*)(ws + 10485760);             // 8M bf16 = 16 MB (reused as xt2)
    u16*   qkvb = (u16*)(ws + 27262976);             // 24M bf16 = 48 MB (reused as ffn hidden)
    u16*   attb = (u16*)(ws + 77594624);             // 8M bf16 = 16 MB
    float* xt   = (float*)(ws + 94371840);           // 8M fp32 = 32 MB

    cvt_w<<<1024, 256, 0, stream>>>(Wq, Wk, Wv, W1, W2, wbf);
    ln_kernel<false><<<8192, 256, 0, stream>>>(x, nullptr, ln1g, ln1b, nullptr, xn);
    gemm_bt<0><<<dim3(64, 24), 256, 0, stream>>>(xn, wbf, qkvb, nullptr, nullptr,
                                                 8192, 3072, 1024);
    attn_fwd<<<dim3(32, 16, 4), 256, 0, stream>>>(qkvb, attb);
    ln_kernel<true><<<8192, 256, 0, stream>>>(x, attb, ln2g, ln2b, xt, xn);
    gemm_bt<1><<<dim3(64, 8), 256, 0, stream>>>(xn, wbf + (3 << 20), qkvb, b1, nullptr,
                                                8192, 1024, 1024);
    gemm_bt<2><<<dim3(64, 8), 256, 0, stream>>>(qkvb, wbf + (4 << 20), d_out, b2, xt,
                                                8192, 1024, 1024);
}

// Round 2
// 418.015 us; speedup vs baseline: 1.3740x; 1.3740x over previous
//
#include <hip/hip_runtime.h>
#include <hip/hip_bf16.h>

typedef unsigned short u16;
typedef __attribute__((ext_vector_type(8))) __bf16 bf16x8;
typedef __attribute__((ext_vector_type(4))) float f32x4;
typedef __attribute__((ext_vector_type(8))) unsigned short ushort8v;
typedef __attribute__((ext_vector_type(4))) unsigned short u16x4;

#define DEV __device__ __forceinline__

DEV u16 f2bf(float f) {
    union { float f; unsigned int i; } u; u.f = f;
    unsigned int x = u.i;
    unsigned int r = (x + 0x7fffu + ((x >> 16) & 1u)) >> 16;
    return (u16)r;
}
DEV float bf2f(u16 h) {
    union { unsigned int i; float f; } u; u.i = ((unsigned int)h) << 16;
    return u.f;
}

// ---------------------------------------------------------------------------
// Weight conversion: pack [Wq;Wk;Wv] as [3072,1024] bf16, then W1, W2.
// ---------------------------------------------------------------------------
__global__ __launch_bounds__(256) void cvt_w(
    const float* __restrict__ wq, const float* __restrict__ wk,
    const float* __restrict__ wv, const float* __restrict__ w1,
    const float* __restrict__ w2, u16* __restrict__ dst)
{
    const int i = (blockIdx.x * 256 + threadIdx.x) * 4;
    if (i >= (1 << 20)) return;
    auto conv4 = [](float4 a) {
        u16x4 r; r[0] = f2bf(a.x); r[1] = f2bf(a.y); r[2] = f2bf(a.z); r[3] = f2bf(a.w);
        return r;
    };
    *(u16x4*)(dst + i)               = conv4(*(const float4*)(wq + i));
    *(u16x4*)(dst + (1 << 20) + i)   = conv4(*(const float4*)(wk + i));
    *(u16x4*)(dst + (2 << 20) + i)   = conv4(*(const float4*)(wv + i));
    *(u16x4*)(dst + (3 << 20) + i)   = conv4(*(const float4*)(w1 + i));
    *(u16x4*)(dst + (4 << 20) + i)   = conv4(*(const float4*)(w2 + i));
}

// ---------------------------------------------------------------------------
// Fused (optional residual-add) + LayerNorm. Row per block (1024 cols).
// ---------------------------------------------------------------------------
template<bool ADD>
__global__ __launch_bounds__(256) void ln_kernel(
    const float* __restrict__ xin, const u16* __restrict__ addbf,
    const float* __restrict__ g, const float* __restrict__ be,
    float* __restrict__ xt_out, u16* __restrict__ y_bf)
{
    const int row = blockIdx.x;
    const int tid = threadIdx.x;
    const size_t base = (size_t)row * 1024 + tid * 4;

    float4 xv = *(const float4*)(xin + base);
    float v[4] = {xv.x, xv.y, xv.z, xv.w};
    if (ADD) {
        u16x4 a = *(const u16x4*)(addbf + base);
        v[0] += bf2f(a[0]); v[1] += bf2f(a[1]); v[2] += bf2f(a[2]); v[3] += bf2f(a[3]);
        float4 o; o.x = v[0]; o.y = v[1]; o.z = v[2]; o.w = v[3];
        *(float4*)(xt_out + base) = o;
    }
    float s = 0.f, ss = 0.f;
    #pragma unroll
    for (int j = 0; j < 4; ++j) { s += v[j]; ss += v[j] * v[j]; }
    #pragma unroll
    for (int o = 32; o > 0; o >>= 1) { s += __shfl_xor(s, o); ss += __shfl_xor(ss, o); }
    __shared__ float red[8];
    const int w = tid >> 6;
    if ((tid & 63) == 0) { red[w * 2] = s; red[w * 2 + 1] = ss; }
    __syncthreads();
    s  = red[0] + red[2] + red[4] + red[6];
    ss = red[1] + red[3] + red[5] + red[7];
    const float mu = s * (1.0f / 1024.0f);
    const float var = ss * (1.0f / 1024.0f) - mu * mu;
    const float rstd = rsqrtf(var + 1e-5f);

    const int col = tid * 4;
    float4 gv = *(const float4*)(g + col);
    float4 bv = *(const float4*)(be + col);
    u16x4 o4;
    o4[0] = f2bf((v[0] - mu) * rstd * gv.x + bv.x);
    o4[1] = f2bf((v[1] - mu) * rstd * gv.y + bv.y);
    o4[2] = f2bf((v[2] - mu) * rstd * gv.z + bv.z);
    o4[3] = f2bf((v[3] - mu) * rstd * gv.w + bv.w);
    *(u16x4*)(y_bf + base) = o4;
}

// ---------------------------------------------------------------------------
// GEMM: C[M,N] = A[M,K] @ Bt[N,K]^T   (A, Bt bf16 row-major)
// 128x128 tile, BK=32, 4 waves (2x2), 4x4 16x16 frags per wave.
// EPI 0: scatter to per-head Q/K/V [B,H,S,64] bf16 regions (N=3072).
// EPI 1: +bias, relu, bf16. EPI 2: +bias +resid, fp32.
// ---------------------------------------------------------------------------
template<int EPI>
__global__ __launch_bounds__(256, 2) void gemm_bt(
    const u16* __restrict__ A, const u16* __restrict__ Bt,
    void* __restrict__ Cout, const float* __restrict__ bias,
    const float* __restrict__ resid, int M, int N, int K)
{
    __shared__ u16 As[128 * 32];
    __shared__ u16 Bs[128 * 32];
    const int tid = threadIdx.x;
    const int l = tid & 63;
    const int w = tid >> 6;
    const int wm = w >> 1, wn = w & 1;
    const int fr = l & 15, fc = l >> 4;
    const size_t rowA0 = (size_t)blockIdx.x * 128;
    const size_t rowB0 = (size_t)blockIdx.y * 128;

    f32x4 acc[4][4] = {};
    const int ldoff = fr * 32 + fc * 8;

    const int nkt = K >> 5;
    for (int kt = 0; kt < nkt; ++kt) {
        __syncthreads();
        const int k0 = kt << 5;
        #pragma unroll
        for (int p = 0; p < 2; ++p) {
            const int rr = p * 64 + w * 16 + (l >> 2);
            const int cc = (l & 3) * 8;
            const u16* ga = A  + (rowA0 + rr) * K + k0 + cc;
            const u16* gb = Bt + (rowB0 + rr) * K + k0 + cc;
            __builtin_amdgcn_global_load_lds(
                (const __attribute__((address_space(1))) void*)ga,
                (__attribute__((address_space(3))) void*)(As + (p * 64 + w * 16) * 32),
                16, 0, 0);
            __builtin_amdgcn_global_load_lds(
                (const __attribute__((address_space(1))) void*)gb,
                (__attribute__((address_space(3))) void*)(Bs + (p * 64 + w * 16) * 32),
                16, 0, 0);
        }
        __syncthreads();
        bf16x8 af[4], bfv[4];
        #pragma unroll
        for (int m = 0; m < 4; ++m)
            af[m] = *(const bf16x8*)(As + (wm * 64 + m * 16) * 32 + ldoff);
        #pragma unroll
        for (int n = 0; n < 4; ++n)
            bfv[n] = *(const bf16x8*)(Bs + (wn * 64 + n * 16) * 32 + ldoff);
        #pragma unroll
        for (int m = 0; m < 4; ++m)
            #pragma unroll
            for (int n = 0; n < 4; ++n)
                acc[m][n] = __builtin_amdgcn_mfma_f32_16x16x32_bf16(
                    af[m], bfv[n], acc[m][n], 0, 0, 0);
    }

    const int r0 = (int)rowA0 + wm * 64;
    const int c0 = (int)rowB0 + wn * 64;
    #pragma unroll
    for (int m = 0; m < 4; ++m) {
        #pragma unroll
        for (int n = 0; n < 4; ++n) {
            const int row = r0 + m * 16 + fc * 4;
            const int col = c0 + n * 16 + fr;
            #pragma unroll
            for (int j = 0; j < 4; ++j) {
                float v = acc[m][n][j];
                if constexpr (EPI == 0) {
                    const int rowj = row + j;
                    const int which = col >> 10;          // 0=Q 1=K 2=V
                    const int hh = (col >> 6) & 15;
                    const int dd = col & 63;
                    const size_t dst = (size_t)which * 8388608 +
                        ((((size_t)(rowj >> 11) * 16 + hh) * 2048 + (rowj & 2047)) * 64 + dd);
                    ((u16*)Cout)[dst] = f2bf(v);
                } else if constexpr (EPI == 1) {
                    const size_t idx = (size_t)(row + j) * N + col;
                    v += bias[col];
                    v = fmaxf(v, 0.0f);
                    ((u16*)Cout)[idx] = f2bf(v);
                } else {
                    const size_t idx = (size_t)(row + j) * N + col;
                    v += bias[col] + resid[idx];
                    ((float*)Cout)[idx] = v;
                }
            }
        }
    }
}

// ---------------------------------------------------------------------------
// Causal flash attention. Per-head Q/K/V in [B*H, S, 64] bf16.
// Block = (qt, h, b): 64 q-rows, 4 waves x 16 rows. KV tiles of 64.
// LDS tiles XOR-swizzled (u16 col ^= (row&7)<<3) -> conflict-free b128 reads.
// K staged via global_load_lds with pre-swizzled global source; V^T and P
// via swizzled scalar writes (<=2-way). Out: bf16 [B,S,1024].
// ---------------------------------------------------------------------------
__global__ __launch_bounds__(256, 2) void attn_fwd(
    const u16* __restrict__ Qh, const u16* __restrict__ Kh,
    const u16* __restrict__ Vh, u16* __restrict__ attout)
{
    __shared__ u16 Ks[64 * 64];      // swizzled [kv][d]
    __shared__ u16 Vt[64 * 64];      // swizzled [d][kv]
    __shared__ u16 Pw[4 * 16 * 64];  // per-wave swizzled [q][kv]

    const int qt = blockIdx.x, h = blockIdx.y, b = blockIdx.z;
    const int tid = threadIdx.x, l = tid & 63, w = tid >> 6;
    const int fr = l & 15, fc = l >> 4;
    const int hb = b * 16 + h;
    const size_t head = (size_t)hb << 17;      // hb * 2048 * 64
    const int qbase = qt * 64 + w * 16;

    // Q fragment, pre-scaled by 1/sqrt(64)
    const u16* qp = Qh + head + (size_t)(qbase + fr) * 64 + fc * 8;
    bf16x8 qf0 = *(const bf16x8*)qp;
    bf16x8 qf1 = *(const bf16x8*)(qp + 32);
    #pragma unroll
    for (int j = 0; j < 8; ++j) {
        qf0[j] = (__bf16)((float)qf0[j] * 0.125f);
        qf1[j] = (__bf16)((float)qf1[j] * 0.125f);
    }

    f32x4 acc_o[4] = {};
    float m_run[4], l_run[4];
    #pragma unroll
    for (int j = 0; j < 4; ++j) { m_run[j] = -3.0e38f; l_run[j] = 0.0f; }

    const int sw = (fr & 7) << 3;     // u16-col xor for LDS rows congruent fr mod 8
    const int col0 = (fc * 8) ^ sw;
    const int col1 = col0 ^ 32;

    // K staging geometry (2 global_load_lds issues per tile)
    const int kr0 = tid >> 3;                              // rows 0..31 (issue 0)
    const int kc  = (8 * (tid & 7)) ^ ((kr0 & 7) << 3);    // swizzled u16 col
    const u16* kb_g = Kh + head;
    const u16* vb_g = Vh + head;

    u16* pw = Pw + w * 1024;

    for (int kt = 0; kt <= qt; ++kt) {
        const int kv0 = kt * 64;
        const bool diag = (kt == qt);
        __syncthreads();
        // ---- stage K[64][64] (swizzled source -> linear LDS dest) ----
        __builtin_amdgcn_global_load_lds(
            (const __attribute__((address_space(1))) void*)(kb_g + (size_t)(kv0 + kr0) * 64 + kc),
            (__attribute__((address_space(3))) void*)(Ks + w * 512), 16, 0, 0);
        __builtin_amdgcn_global_load_lds(
            (const __attribute__((address_space(1))) void*)(kb_g + (size_t)(kv0 + 32 + kr0) * 64 + kc),
            (__attribute__((address_space(3))) void*)(Ks + 2048 + w * 512), 16, 0, 0);
        // ---- stage V^T via swizzled scalar writes ----
        {
            const u16* gv = vb_g + (size_t)(kv0 + l) * 64 + w * 16;
            ushort8v v0 = *(const ushort8v*)gv;
            ushort8v v1 = *(const ushort8v*)(gv + 8);
            #pragma unroll
            for (int j = 0; j < 8; ++j) {
                const int d0 = w * 16 + j;
                const int d1 = d0 + 8;
                Vt[d0 * 64 + (l ^ ((d0 & 7) << 3))] = v0[j];
                Vt[d1 * 64 + (l ^ ((d1 & 7) << 3))] = v1[j];
            }
        }
        __syncthreads();

        // ---- S = Q K^T : 4 n-blocks of 16 kv ----
        f32x4 sa[4] = {};
        #pragma unroll
        for (int nb = 0; nb < 4; ++nb) {
            const u16* kb = Ks + (nb * 16 + fr) * 64;
            sa[nb] = __builtin_amdgcn_mfma_f32_16x16x32_bf16(
                qf0, *(const bf16x8*)(kb + col0), sa[nb], 0, 0, 0);
            sa[nb] = __builtin_amdgcn_mfma_f32_16x16x32_bf16(
                qf1, *(const bf16x8*)(kb + col1), sa[nb], 0, 0, 0);
        }

        // ---- online softmax ----
        float p[4][4], mx[4];
        #pragma unroll
        for (int j = 0; j < 4; ++j) {
            #pragma unroll
            for (int nb = 0; nb < 4; ++nb) {
                float s = sa[nb][j];
                if (diag) {
                    const int kg = kv0 + nb * 16 + fr;
                    const int qg = qbase + fc * 4 + j;
                    if (kg > qg) s = -3.0e38f;
                }
                p[nb][j] = s;
            }
            mx[j] = fmaxf(fmaxf(p[0][j], p[1][j]), fmaxf(p[2][j], p[3][j]));
        }
        #pragma unroll
        for (int o = 1; o < 16; o <<= 1)
            #pragma unroll
            for (int j = 0; j < 4; ++j)
                mx[j] = fmaxf(mx[j], __shfl_xor(mx[j], o));

        float alpha[4], rs[4];
        #pragma unroll
        for (int j = 0; j < 4; ++j) {
            const float mn = fmaxf(m_run[j], mx[j]);
            alpha[j] = __expf(m_run[j] - mn);
            m_run[j] = mn;
            const float e0 = __expf(p[0][j] - mn);
            const float e1 = __expf(p[1][j] - mn);
            const float e2 = __expf(p[2][j] - mn);
            const float e3 = __expf(p[3][j] - mn);
            p[0][j] = e0; p[1][j] = e1; p[2][j] = e2; p[3][j] = e3;
            rs[j] = (e0 + e1) + (e2 + e3);
        }
        #pragma unroll
        for (int o = 1; o < 16; o <<= 1)
            #pragma unroll
            for (int j = 0; j < 4; ++j)
                rs[j] += __shfl_xor(rs[j], o);
        #pragma unroll
        for (int j = 0; j < 4; ++j)
            l_run[j] = l_run[j] * alpha[j] + rs[j];
        #pragma unroll
        for (int db = 0; db < 4; ++db)
            #pragma unroll
            for (int j = 0; j < 4; ++j)
                acc_o[db][j] *= alpha[j];

        // ---- P -> per-wave LDS (no barrier needed), then PV ----
        #pragma unroll
        for (int j = 0; j < 4; ++j) {
            const int q = fc * 4 + j;
            u16* prow = pw + q * 64;
            const int qx = (q & 7) << 3;
            #pragma unroll
            for (int nb = 0; nb < 4; ++nb)
                prow[(nb * 16 + fr) ^ qx] = f2bf(p[nb][j]);
        }
        const u16* prd = pw + fr * 64;
        const bf16x8 pf0 = *(const bf16x8*)(prd + col0);
        const bf16x8 pf1 = *(const bf16x8*)(prd + col1);
        #pragma unroll
        for (int db = 0; db < 4; ++db) {
            const u16* vb = Vt + (db * 16 + fr) * 64;
            acc_o[db] = __builtin_amdgcn_mfma_f32_16x16x32_bf16(
                pf0, *(const bf16x8*)(vb + col0), acc_o[db], 0, 0, 0);
            acc_o[db] = __builtin_amdgcn_mfma_f32_16x16x32_bf16(
                pf1, *(const bf16x8*)(vb + col1), acc_o[db], 0, 0, 0);
        }
    }

    float inv[4];
    #pragma unroll
    for (int j = 0; j < 4; ++j) inv[j] = 1.0f / l_run[j];
    const size_t bS = (size_t)b * 2048;
    #pragma unroll
    for (int db = 0; db < 4; ++db)
        #pragma unroll
        for (int j = 0; j < 4; ++j)
            attout[(bS + qbase + fc * 4 + j) * 1024 + h * 64 + db * 16 + fr] =
                f2bf(acc_o[db][j] * inv[j]);
}

// ---------------------------------------------------------------------------
extern "C" void kernel_launch(void* const* d_in, const int* in_sizes, int n_in,
                              void* d_out, int out_size, void* d_ws, size_t ws_size,
                              hipStream_t stream)
{
    const float* x    = (const float*)d_in[0];
    const float* Wq   = (const float*)d_in[1];
    const float* Wk   = (const float*)d_in[2];
    const float* Wv   = (const float*)d_in[3];
    const float* ln1g = (const float*)d_in[4];
    const float* ln1b = (const float*)d_in[5];
    const float* ln2g = (const float*)d_in[6];
    const float* ln2b = (const float*)d_in[7];
    const float* W1   = (const float*)d_in[8];
    const float* b1   = (const float*)d_in[9];
    const float* W2   = (const float*)d_in[10];
    const float* b2   = (const float*)d_in[11];

    char* ws = (char*)d_ws;
    u16*   wbf  = (u16*)(ws);                        // 5M bf16 = 10 MB
    u16*   xn   = (u16*)(ws + 10485760);             // 8M bf16 = 16 MB (reused as xt2)
    u16*   qkvb = (u16*)(ws + 27262976);             // 24M bf16 = 48 MB (reused as ffn hidden)
    u16*   attb = (u16*)(ws + 77594624);             // 8M bf16 = 16 MB
    float* xt   = (float*)(ws + 94371840);           // 8M fp32 = 32 MB

    cvt_w<<<1024, 256, 0, stream>>>(Wq, Wk, Wv, W1, W2, wbf);
    ln_kernel<false><<<8192, 256, 0, stream>>>(x, nullptr, ln1g, ln1b, nullptr, xn);
    gemm_bt<0><<<dim3(64, 24), 256, 0, stream>>>(xn, wbf, qkvb, nullptr, nullptr,
                                                 8192, 3072, 1024);
    attn_fwd<<<dim3(32, 16, 4), 256, 0, stream>>>(qkvb, qkvb + 8388608, qkvb + 16777216,
                                                  attb);
    ln_kernel<true><<<8192, 256, 0, stream>>>(x, attb, ln2g, ln2b, xt, xn);
    gemm_bt<1><<<dim3(64, 8), 256, 0, stream>>>(xn, wbf + (3 << 20), qkvb, b1, nullptr,
                                                8192, 1024, 1024);
    gemm_bt<2><<<dim3(64, 8), 256, 0, stream>>>(qkvb, wbf + (4 << 20), d_out, b2, xt,
                                                8192, 1024, 1024);
}

// Round 3
// 299.505 us; speedup vs baseline: 1.9176x; 1.3957x over previous
//
#include <hip/hip_runtime.h>
#include <hip/hip_bf16.h>

typedef unsigned short u16;
typedef __attribute__((ext_vector_type(8))) __bf16 bf16x8;
typedef __attribute__((ext_vector_type(4))) float f32x4;
typedef __attribute__((ext_vector_type(8))) unsigned short ushort8v;
typedef __attribute__((ext_vector_type(4))) unsigned short u16x4;

#define DEV __device__ __forceinline__

DEV u16 f2bf(float f) {
    union { float f; unsigned int i; } u; u.f = f;
    unsigned int x = u.i;
    unsigned int r = (x + 0x7fffu + ((x >> 16) & 1u)) >> 16;
    return (u16)r;
}
DEV float bf2f(u16 h) {
    union { unsigned int i; float f; } u; u.i = ((unsigned int)h) << 16;
    return u.f;
}

// ---------------------------------------------------------------------------
// Weight conversion: pack [Wq;Wk;Wv] as [3072,1024] bf16, then W1, W2.
// ---------------------------------------------------------------------------
__global__ __launch_bounds__(256) void cvt_w(
    const float* __restrict__ wq, const float* __restrict__ wk,
    const float* __restrict__ wv, const float* __restrict__ w1,
    const float* __restrict__ w2, u16* __restrict__ dst)
{
    const int i = (blockIdx.x * 256 + threadIdx.x) * 4;
    if (i >= (1 << 20)) return;
    auto conv4 = [](float4 a) {
        u16x4 r; r[0] = f2bf(a.x); r[1] = f2bf(a.y); r[2] = f2bf(a.z); r[3] = f2bf(a.w);
        return r;
    };
    *(u16x4*)(dst + i)               = conv4(*(const float4*)(wq + i));
    *(u16x4*)(dst + (1 << 20) + i)   = conv4(*(const float4*)(wk + i));
    *(u16x4*)(dst + (2 << 20) + i)   = conv4(*(const float4*)(wv + i));
    *(u16x4*)(dst + (3 << 20) + i)   = conv4(*(const float4*)(w1 + i));
    *(u16x4*)(dst + (4 << 20) + i)   = conv4(*(const float4*)(w2 + i));
}

// ---------------------------------------------------------------------------
// Fused (optional residual-add) + LayerNorm. Row per block (1024 cols).
// ---------------------------------------------------------------------------
template<bool ADD>
__global__ __launch_bounds__(256) void ln_kernel(
    const float* __restrict__ xin, const u16* __restrict__ addbf,
    const float* __restrict__ g, const float* __restrict__ be,
    float* __restrict__ xt_out, u16* __restrict__ y_bf)
{
    const int row = blockIdx.x;
    const int tid = threadIdx.x;
    const size_t base = (size_t)row * 1024 + tid * 4;

    float4 xv = *(const float4*)(xin + base);
    float v[4] = {xv.x, xv.y, xv.z, xv.w};
    if (ADD) {
        u16x4 a = *(const u16x4*)(addbf + base);
        v[0] += bf2f(a[0]); v[1] += bf2f(a[1]); v[2] += bf2f(a[2]); v[3] += bf2f(a[3]);
        float4 o; o.x = v[0]; o.y = v[1]; o.z = v[2]; o.w = v[3];
        *(float4*)(xt_out + base) = o;
    }
    float s = 0.f, ss = 0.f;
    #pragma unroll
    for (int j = 0; j < 4; ++j) { s += v[j]; ss += v[j] * v[j]; }
    #pragma unroll
    for (int o = 32; o > 0; o >>= 1) { s += __shfl_xor(s, o); ss += __shfl_xor(ss, o); }
    __shared__ float red[8];
    const int w = tid >> 6;
    if ((tid & 63) == 0) { red[w * 2] = s; red[w * 2 + 1] = ss; }
    __syncthreads();
    s  = red[0] + red[2] + red[4] + red[6];
    ss = red[1] + red[3] + red[5] + red[7];
    const float mu = s * (1.0f / 1024.0f);
    const float var = ss * (1.0f / 1024.0f) - mu * mu;
    const float rstd = rsqrtf(var + 1e-5f);

    const int col = tid * 4;
    float4 gv = *(const float4*)(g + col);
    float4 bv = *(const float4*)(be + col);
    u16x4 o4;
    o4[0] = f2bf((v[0] - mu) * rstd * gv.x + bv.x);
    o4[1] = f2bf((v[1] - mu) * rstd * gv.y + bv.y);
    o4[2] = f2bf((v[2] - mu) * rstd * gv.z + bv.z);
    o4[3] = f2bf((v[3] - mu) * rstd * gv.w + bv.w);
    *(u16x4*)(y_bf + base) = o4;
}

// ---------------------------------------------------------------------------
// GEMM: C[M,N] = A[M,K] @ Bt[N,K]^T   (A, Bt bf16 row-major)
// 128x128 tile, BK=32, 4 waves (2x2), 4x4 16x16 frags per wave.
// EPI 0: scatter to per-head Q/K/V [B,H,S,64] bf16 regions (N=3072).
// EPI 1: +bias, relu, bf16. EPI 2: +bias +resid, fp32.
// ---------------------------------------------------------------------------
template<int EPI>
__global__ __launch_bounds__(256, 2) void gemm_bt(
    const u16* __restrict__ A, const u16* __restrict__ Bt,
    void* __restrict__ Cout, const float* __restrict__ bias,
    const float* __restrict__ resid, int M, int N, int K)
{
    __shared__ u16 As[128 * 32];
    __shared__ u16 Bs[128 * 32];
    const int tid = threadIdx.x;
    const int l = tid & 63;
    const int w = tid >> 6;
    const int wm = w >> 1, wn = w & 1;
    const int fr = l & 15, fc = l >> 4;
    const size_t rowA0 = (size_t)blockIdx.x * 128;
    const size_t rowB0 = (size_t)blockIdx.y * 128;

    f32x4 acc[4][4] = {};
    const int ldoff = fr * 32 + fc * 8;

    const int nkt = K >> 5;
    for (int kt = 0; kt < nkt; ++kt) {
        __syncthreads();
        const int k0 = kt << 5;
        #pragma unroll
        for (int p = 0; p < 2; ++p) {
            const int rr = p * 64 + w * 16 + (l >> 2);
            const int cc = (l & 3) * 8;
            const u16* ga = A  + (rowA0 + rr) * K + k0 + cc;
            const u16* gb = Bt + (rowB0 + rr) * K + k0 + cc;
            __builtin_amdgcn_global_load_lds(
                (const __attribute__((address_space(1))) void*)ga,
                (__attribute__((address_space(3))) void*)(As + (p * 64 + w * 16) * 32),
                16, 0, 0);
            __builtin_amdgcn_global_load_lds(
                (const __attribute__((address_space(1))) void*)gb,
                (__attribute__((address_space(3))) void*)(Bs + (p * 64 + w * 16) * 32),
                16, 0, 0);
        }
        __syncthreads();
        bf16x8 af[4], bfv[4];
        #pragma unroll
        for (int m = 0; m < 4; ++m)
            af[m] = *(const bf16x8*)(As + (wm * 64 + m * 16) * 32 + ldoff);
        #pragma unroll
        for (int n = 0; n < 4; ++n)
            bfv[n] = *(const bf16x8*)(Bs + (wn * 64 + n * 16) * 32 + ldoff);
        #pragma unroll
        for (int m = 0; m < 4; ++m)
            #pragma unroll
            for (int n = 0; n < 4; ++n)
                acc[m][n] = __builtin_amdgcn_mfma_f32_16x16x32_bf16(
                    af[m], bfv[n], acc[m][n], 0, 0, 0);
    }

    const int r0 = (int)rowA0 + wm * 64;
    const int c0 = (int)rowB0 + wn * 64;
    #pragma unroll
    for (int m = 0; m < 4; ++m) {
        #pragma unroll
        for (int n = 0; n < 4; ++n) {
            const int row = r0 + m * 16 + fc * 4;
            const int col = c0 + n * 16 + fr;
            #pragma unroll
            for (int j = 0; j < 4; ++j) {
                float v = acc[m][n][j];
                if constexpr (EPI == 0) {
                    const int rowj = row + j;
                    const int which = col >> 10;          // 0=Q 1=K 2=V
                    const int hh = (col >> 6) & 15;
                    const int dd = col & 63;
                    const size_t dst = (size_t)which * 8388608 +
                        ((((size_t)(rowj >> 11) * 16 + hh) * 2048 + (rowj & 2047)) * 64 + dd);
                    ((u16*)Cout)[dst] = f2bf(v);
                } else if constexpr (EPI == 1) {
                    const size_t idx = (size_t)(row + j) * N + col;
                    v += bias[col];
                    v = fmaxf(v, 0.0f);
                    ((u16*)Cout)[idx] = f2bf(v);
                } else {
                    const size_t idx = (size_t)(row + j) * N + col;
                    v += bias[col] + resid[idx];
                    ((float*)Cout)[idx] = v;
                }
            }
        }
    }
}

// ---------------------------------------------------------------------------
// Causal flash attention, load-balanced + async-staged.
// Per-head Q/K/V in [B*H, S, 64] bf16. Block = (pair, h, b) processes
// q-tiles {pair, 31-pair} sequentially -> uniform 33 kv-tiles per block.
// 4 waves x 16 q-rows, KV tiles of 64. K/V reg-staged (T14): next tile's
// global loads issued under current tile's compute. LDS XOR-swizzled
// (u16 col ^= (row&7)<<3) -> conflict-free ds_read_b128. Softmax in exp2
// domain. Out: bf16 [B,S,1024].
// ---------------------------------------------------------------------------
__global__ __launch_bounds__(256, 4) void attn_fwd(
    const u16* __restrict__ Qh, const u16* __restrict__ Kh,
    const u16* __restrict__ Vh, u16* __restrict__ attout)
{
    __shared__ u16 Ks[64 * 64];      // swizzled [kv][d]
    __shared__ u16 Vt[64 * 64];      // swizzled [d][kv]
    __shared__ u16 Pw[4 * 16 * 64];  // per-wave swizzled [q][kv]

    const int pair = blockIdx.x, h = blockIdx.y, b = blockIdx.z;
    const int tid = threadIdx.x, l = tid & 63, w = tid >> 6;
    const int fr = l & 15, fc = l >> 4;
    const int hb = b * 16 + h;
    const size_t head = (size_t)hb << 17;      // hb * 2048 * 64
    const u16* kb_g = Kh + head;
    const u16* vb_g = Vh + head;
    u16* pw = Pw + w * 1024;

    const int sw = (fr & 7) << 3;
    const int col0 = (fc * 8) ^ sw;
    const int col1 = col0 ^ 32;

    // reg-staging geometry: thread stages 32B of K row kr and V row kr
    const int kr = tid >> 2;               // 0..63
    const int kc0 = (tid & 3) * 16;        // u16 col of first 8-chunk
    const int kd0 = kc0 ^ ((kr & 7) << 3);
    const int kd1 = (kc0 + 8) ^ ((kr & 7) << 3);

    const float qs = 0.125f * 1.44269504f;  // 1/sqrt(64) * log2(e)

    #pragma unroll 1
    for (int half = 0; half < 2; ++half) {
        const int qt = half ? 31 - pair : pair;
        const int qbase = qt * 64 + w * 16;

        const u16* qp = Qh + head + (size_t)(qbase + fr) * 64 + fc * 8;
        bf16x8 qf0 = *(const bf16x8*)qp;
        bf16x8 qf1 = *(const bf16x8*)(qp + 32);
        #pragma unroll
        for (int j = 0; j < 8; ++j) {
            qf0[j] = (__bf16)((float)qf0[j] * qs);
            qf1[j] = (__bf16)((float)qf1[j] * qs);
        }

        f32x4 acc_o[4] = {};
        float m_run[4], l_run[4];
        #pragma unroll
        for (int j = 0; j < 4; ++j) { m_run[j] = -3.0e38f; l_run[j] = 0.0f; }

        const int nkt = qt + 1;
        // prologue: issue tile-0 loads
        ushort8v kA = *(const ushort8v*)(kb_g + (size_t)kr * 64 + kc0);
        ushort8v kB = *(const ushort8v*)(kb_g + (size_t)kr * 64 + kc0 + 8);
        ushort8v vA = *(const ushort8v*)(vb_g + (size_t)kr * 64 + kc0);
        ushort8v vB = *(const ushort8v*)(vb_g + (size_t)kr * 64 + kc0 + 8);

        #pragma unroll 1
        for (int kt = 0; kt < nkt; ++kt) {
            const int kv0 = kt * 64;
            const bool diag = (kt == qt);
            __syncthreads();            // all waves done reading prev tile LDS
            // ---- write staged K (b128, swizzled) ----
            *(ushort8v*)(Ks + kr * 64 + kd0) = kA;
            *(ushort8v*)(Ks + kr * 64 + kd1) = kB;
            // ---- write staged V transposed (scalar, swizzled) ----
            #pragma unroll
            for (int j = 0; j < 8; ++j) {
                const int d0 = kc0 + j, d1 = kc0 + 8 + j;
                Vt[d0 * 64 + (kr ^ ((d0 & 7) << 3))] = vA[j];
                Vt[d1 * 64 + (kr ^ ((d1 & 7) << 3))] = vB[j];
            }
            __syncthreads();            // tile ready
            // ---- issue next tile's loads (hidden under compute) ----
            if (kt + 1 < nkt) {
                const u16* kn = kb_g + (size_t)(kv0 + 64 + kr) * 64 + kc0;
                const u16* vn = vb_g + (size_t)(kv0 + 64 + kr) * 64 + kc0;
                kA = *(const ushort8v*)kn; kB = *(const ushort8v*)(kn + 8);
                vA = *(const ushort8v*)vn; vB = *(const ushort8v*)(vn + 8);
            }

            // ---- S = Q K^T : 4 n-blocks of 16 kv ----
            f32x4 sa[4] = {};
            #pragma unroll
            for (int nb = 0; nb < 4; ++nb) {
                const u16* kb = Ks + (nb * 16 + fr) * 64;
                sa[nb] = __builtin_amdgcn_mfma_f32_16x16x32_bf16(
                    qf0, *(const bf16x8*)(kb + col0), sa[nb], 0, 0, 0);
                sa[nb] = __builtin_amdgcn_mfma_f32_16x16x32_bf16(
                    qf1, *(const bf16x8*)(kb + col1), sa[nb], 0, 0, 0);
            }

            // ---- online softmax (exp2 domain) ----
            float mx[4];
            #pragma unroll
            for (int j = 0; j < 4; ++j) {
                if (diag) {
                    const int qg = qbase + fc * 4 + j;
                    #pragma unroll
                    for (int nb = 0; nb < 4; ++nb) {
                        const int kg = kv0 + nb * 16 + fr;
                        if (kg > qg) sa[nb][j] = -3.0e38f;
                    }
                }
                mx[j] = fmaxf(fmaxf(sa[0][j], sa[1][j]), fmaxf(sa[2][j], sa[3][j]));
            }
            #pragma unroll
            for (int o = 1; o < 16; o <<= 1)
                #pragma unroll
                for (int j = 0; j < 4; ++j)
                    mx[j] = fmaxf(mx[j], __shfl_xor(mx[j], o));

            float alpha[4], rs[4];
            #pragma unroll
            for (int j = 0; j < 4; ++j) {
                const float mn = fmaxf(m_run[j], mx[j]);
                alpha[j] = exp2f(m_run[j] - mn);
                m_run[j] = mn;
                float e0 = exp2f(sa[0][j] - mn);
                float e1 = exp2f(sa[1][j] - mn);
                float e2 = exp2f(sa[2][j] - mn);
                float e3 = exp2f(sa[3][j] - mn);
                sa[0][j] = e0; sa[1][j] = e1; sa[2][j] = e2; sa[3][j] = e3;
                rs[j] = (e0 + e1) + (e2 + e3);
            }
            #pragma unroll
            for (int o = 1; o < 16; o <<= 1)
                #pragma unroll
                for (int j = 0; j < 4; ++j)
                    rs[j] += __shfl_xor(rs[j], o);
            #pragma unroll
            for (int j = 0; j < 4; ++j)
                l_run[j] = l_run[j] * alpha[j] + rs[j];
            #pragma unroll
            for (int db = 0; db < 4; ++db)
                #pragma unroll
                for (int j = 0; j < 4; ++j)
                    acc_o[db][j] *= alpha[j];

            // ---- P -> per-wave LDS (same-wave ordering, no barrier), PV ----
            #pragma unroll
            for (int j = 0; j < 4; ++j) {
                const int q = fc * 4 + j;
                u16* prow = pw + q * 64;
                const int qx = (q & 7) << 3;
                #pragma unroll
                for (int nb = 0; nb < 4; ++nb)
                    prow[(nb * 16 + fr) ^ qx] = f2bf(sa[nb][j]);
            }
            const u16* prd = pw + fr * 64;
            const bf16x8 pf0 = *(const bf16x8*)(prd + col0);
            const bf16x8 pf1 = *(const bf16x8*)(prd + col1);
            #pragma unroll
            for (int db = 0; db < 4; ++db) {
                const u16* vb = Vt + (db * 16 + fr) * 64;
                acc_o[db] = __builtin_amdgcn_mfma_f32_16x16x32_bf16(
                    pf0, *(const bf16x8*)(vb + col0), acc_o[db], 0, 0, 0);
                acc_o[db] = __builtin_amdgcn_mfma_f32_16x16x32_bf16(
                    pf1, *(const bf16x8*)(vb + col1), acc_o[db], 0, 0, 0);
            }
        }

        float inv[4];
        #pragma unroll
        for (int j = 0; j < 4; ++j) inv[j] = 1.0f / l_run[j];
        const size_t bS = (size_t)b * 2048;
        #pragma unroll
        for (int db = 0; db < 4; ++db)
            #pragma unroll
            for (int j = 0; j < 4; ++j)
                attout[(bS + qbase + fc * 4 + j) * 1024 + h * 64 + db * 16 + fr] =
                    f2bf(acc_o[db][j] * inv[j]);
    }
}

// ---------------------------------------------------------------------------
extern "C" void kernel_launch(void* const* d_in, const int* in_sizes, int n_in,
                              void* d_out, int out_size, void* d_ws, size_t ws_size,
                              hipStream_t stream)
{
    const float* x    = (const float*)d_in[0];
    const float* Wq   = (const float*)d_in[1];
    const float* Wk   = (const float*)d_in[2];
    const float* Wv   = (const float*)d_in[3];
    const float* ln1g = (const float*)d_in[4];
    const float* ln1b = (const float*)d_in[5];
    const float* ln2g = (const float*)d_in[6];
    const float* ln2b = (const float*)d_in[7];
    const float* W1   = (const float*)d_in[8];
    const float* b1   = (const float*)d_in[9];
    const float* W2   = (const float*)d_in[10];
    const float* b2   = (const float*)d_in[11];

    char* ws = (char*)d_ws;
    u16*   wbf  = (u16*)(ws);                        // 5M bf16 = 10 MB
    u16*   xn   = (u16*)(ws + 10485760);             // 8M bf16 = 16 MB (reused as xt2)
    u16*   qkvb = (u16*)(ws + 27262976);             // 24M bf16 = 48 MB (reused as ffn hidden)
    u16*   attb = (u16*)(ws + 77594624);             // 8M bf16 = 16 MB
    float* xt   = (float*)(ws + 94371840);           // 8M fp32 = 32 MB

    cvt_w<<<1024, 256, 0, stream>>>(Wq, Wk, Wv, W1, W2, wbf);
    ln_kernel<false><<<8192, 256, 0, stream>>>(x, nullptr, ln1g, ln1b, nullptr, xn);
    gemm_bt<0><<<dim3(64, 24), 256, 0, stream>>>(xn, wbf, qkvb, nullptr, nullptr,
                                                 8192, 3072, 1024);
    attn_fwd<<<dim3(16, 16, 4), 256, 0, stream>>>(qkvb, qkvb + 8388608, qkvb + 16777216,
                                                  attb);
    ln_kernel<true><<<8192, 256, 0, stream>>>(x, attb, ln2g, ln2b, xt, xn);
    gemm_bt<1><<<dim3(64, 8), 256, 0, stream>>>(xn, wbf + (3 << 20), qkvb, b1, nullptr,
                                                8192, 1024, 1024);
    gemm_bt<2><<<dim3(64, 8), 256, 0, stream>>>(qkvb, wbf + (4 << 20), d_out, b2, xt,
                                                8192, 1024, 1024);
}

// Round 4
// 276.182 us; speedup vs baseline: 2.0796x; 1.0844x over previous
//
#include <hip/hip_runtime.h>
#include <hip/hip_bf16.h>

typedef unsigned short u16;
typedef __attribute__((ext_vector_type(8))) __bf16 bf16x8;
typedef __attribute__((ext_vector_type(4))) float f32x4;
typedef __attribute__((ext_vector_type(8))) unsigned short ushort8v;
typedef __attribute__((ext_vector_type(4))) unsigned short u16x4;

#define DEV __device__ __forceinline__

DEV u16 f2bf(float f) {
    union { float f; unsigned int i; } u; u.f = f;
    unsigned int x = u.i;
    unsigned int r = (x + 0x7fffu + ((x >> 16) & 1u)) >> 16;
    return (u16)r;
}
DEV float bf2f(u16 h) {
    union { unsigned int i; float f; } u; u.i = ((unsigned int)h) << 16;
    return u.f;
}

// ---------------------------------------------------------------------------
// Weight conversion: pack [Wq;Wk;Wv] as [3072,1024] bf16, then W1, W2.
// ---------------------------------------------------------------------------
__global__ __launch_bounds__(256) void cvt_w(
    const float* __restrict__ wq, const float* __restrict__ wk,
    const float* __restrict__ wv, const float* __restrict__ w1,
    const float* __restrict__ w2, u16* __restrict__ dst)
{
    const int i = (blockIdx.x * 256 + threadIdx.x) * 4;
    if (i >= (1 << 20)) return;
    auto conv4 = [](float4 a) {
        u16x4 r; r[0] = f2bf(a.x); r[1] = f2bf(a.y); r[2] = f2bf(a.z); r[3] = f2bf(a.w);
        return r;
    };
    *(u16x4*)(dst + i)               = conv4(*(const float4*)(wq + i));
    *(u16x4*)(dst + (1 << 20) + i)   = conv4(*(const float4*)(wk + i));
    *(u16x4*)(dst + (2 << 20) + i)   = conv4(*(const float4*)(wv + i));
    *(u16x4*)(dst + (3 << 20) + i)   = conv4(*(const float4*)(w1 + i));
    *(u16x4*)(dst + (4 << 20) + i)   = conv4(*(const float4*)(w2 + i));
}

// ---------------------------------------------------------------------------
// Fused (optional residual-add) + LayerNorm. Row per block (1024 cols).
// ---------------------------------------------------------------------------
template<bool ADD>
__global__ __launch_bounds__(256) void ln_kernel(
    const float* __restrict__ xin, const u16* __restrict__ addbf,
    const float* __restrict__ g, const float* __restrict__ be,
    float* __restrict__ xt_out, u16* __restrict__ y_bf)
{
    const int row = blockIdx.x;
    const int tid = threadIdx.x;
    const size_t base = (size_t)row * 1024 + tid * 4;

    float4 xv = *(const float4*)(xin + base);
    float v[4] = {xv.x, xv.y, xv.z, xv.w};
    if (ADD) {
        u16x4 a = *(const u16x4*)(addbf + base);
        v[0] += bf2f(a[0]); v[1] += bf2f(a[1]); v[2] += bf2f(a[2]); v[3] += bf2f(a[3]);
        float4 o; o.x = v[0]; o.y = v[1]; o.z = v[2]; o.w = v[3];
        *(float4*)(xt_out + base) = o;
    }
    float s = 0.f, ss = 0.f;
    #pragma unroll
    for (int j = 0; j < 4; ++j) { s += v[j]; ss += v[j] * v[j]; }
    #pragma unroll
    for (int o = 32; o > 0; o >>= 1) { s += __shfl_xor(s, o); ss += __shfl_xor(ss, o); }
    __shared__ float red[8];
    const int w = tid >> 6;
    if ((tid & 63) == 0) { red[w * 2] = s; red[w * 2 + 1] = ss; }
    __syncthreads();
    s  = red[0] + red[2] + red[4] + red[6];
    ss = red[1] + red[3] + red[5] + red[7];
    const float mu = s * (1.0f / 1024.0f);
    const float var = ss * (1.0f / 1024.0f) - mu * mu;
    const float rstd = rsqrtf(var + 1e-5f);

    const int col = tid * 4;
    float4 gv = *(const float4*)(g + col);
    float4 bv = *(const float4*)(be + col);
    u16x4 o4;
    o4[0] = f2bf((v[0] - mu) * rstd * gv.x + bv.x);
    o4[1] = f2bf((v[1] - mu) * rstd * gv.y + bv.y);
    o4[2] = f2bf((v[2] - mu) * rstd * gv.z + bv.z);
    o4[3] = f2bf((v[3] - mu) * rstd * gv.w + bv.w);
    *(u16x4*)(y_bf + base) = o4;
}

// ---------------------------------------------------------------------------
// GEMM: C[M,N] = A[M,K] @ Bt[N,K]^T   (A, Bt bf16 row-major)
// 128x128 tile, BK=32, 4 waves (2x2), 4x4 16x16 frags per wave.
// EPI 0: scatter to per-head Q/K/V [B,H,S,64] bf16 regions (N=3072).
// EPI 1: +bias, relu, bf16. EPI 2: +bias +resid, fp32.
// ---------------------------------------------------------------------------
template<int EPI>
__global__ __launch_bounds__(256, 2) void gemm_bt(
    const u16* __restrict__ A, const u16* __restrict__ Bt,
    void* __restrict__ Cout, const float* __restrict__ bias,
    const float* __restrict__ resid, int M, int N, int K)
{
    __shared__ u16 As[128 * 32];
    __shared__ u16 Bs[128 * 32];
    const int tid = threadIdx.x;
    const int l = tid & 63;
    const int w = tid >> 6;
    const int wm = w >> 1, wn = w & 1;
    const int fr = l & 15, fc = l >> 4;
    const size_t rowA0 = (size_t)blockIdx.x * 128;
    const size_t rowB0 = (size_t)blockIdx.y * 128;

    f32x4 acc[4][4] = {};
    const int ldoff = fr * 32 + fc * 8;

    const int nkt = K >> 5;
    for (int kt = 0; kt < nkt; ++kt) {
        __syncthreads();
        const int k0 = kt << 5;
        #pragma unroll
        for (int p = 0; p < 2; ++p) {
            const int rr = p * 64 + w * 16 + (l >> 2);
            const int cc = (l & 3) * 8;
            const u16* ga = A  + (rowA0 + rr) * K + k0 + cc;
            const u16* gb = Bt + (rowB0 + rr) * K + k0 + cc;
            __builtin_amdgcn_global_load_lds(
                (const __attribute__((address_space(1))) void*)ga,
                (__attribute__((address_space(3))) void*)(As + (p * 64 + w * 16) * 32),
                16, 0, 0);
            __builtin_amdgcn_global_load_lds(
                (const __attribute__((address_space(1))) void*)gb,
                (__attribute__((address_space(3))) void*)(Bs + (p * 64 + w * 16) * 32),
                16, 0, 0);
        }
        __syncthreads();
        bf16x8 af[4], bfv[4];
        #pragma unroll
        for (int m = 0; m < 4; ++m)
            af[m] = *(const bf16x8*)(As + (wm * 64 + m * 16) * 32 + ldoff);
        #pragma unroll
        for (int n = 0; n < 4; ++n)
            bfv[n] = *(const bf16x8*)(Bs + (wn * 64 + n * 16) * 32 + ldoff);
        #pragma unroll
        for (int m = 0; m < 4; ++m)
            #pragma unroll
            for (int n = 0; n < 4; ++n)
                acc[m][n] = __builtin_amdgcn_mfma_f32_16x16x32_bf16(
                    af[m], bfv[n], acc[m][n], 0, 0, 0);
    }

    const int r0 = (int)rowA0 + wm * 64;
    const int c0 = (int)rowB0 + wn * 64;
    #pragma unroll
    for (int m = 0; m < 4; ++m) {
        #pragma unroll
        for (int n = 0; n < 4; ++n) {
            const int row = r0 + m * 16 + fc * 4;
            const int col = c0 + n * 16 + fr;
            #pragma unroll
            for (int j = 0; j < 4; ++j) {
                float v = acc[m][n][j];
                if constexpr (EPI == 0) {
                    const int rowj = row + j;
                    const int which = col >> 10;          // 0=Q 1=K 2=V
                    const int hh = (col >> 6) & 15;
                    const int dd = col & 63;
                    const size_t dst = (size_t)which * 8388608 +
                        ((((size_t)(rowj >> 11) * 16 + hh) * 2048 + (rowj & 2047)) * 64 + dd);
                    ((u16*)Cout)[dst] = f2bf(v);
                } else if constexpr (EPI == 1) {
                    const size_t idx = (size_t)(row + j) * N + col;
                    v += bias[col];
                    v = fmaxf(v, 0.0f);
                    ((u16*)Cout)[idx] = f2bf(v);
                } else {
                    const size_t idx = (size_t)(row + j) * N + col;
                    v += bias[col] + resid[idx];
                    ((float*)Cout)[idx] = v;
                }
            }
        }
    }
}

// ---------------------------------------------------------------------------
// Causal flash attention, load-balanced + async-staged + XCD-colocated.
// Per-head Q/K/V in [B*H, S, 64] bf16. 1-D grid of 1024; decode puts all
// 16 pair-blocks of one (h,b) on the same XCD (bid&7 = head-group % 8).
// Block processes q-tiles {pair, 31-pair} -> uniform 33 kv-tiles.
// 4 waves x 16 q-rows, KV tiles of 64. K/V reg-staged (T14). LDS
// XOR-swizzled; V adds (d>>4)<<4 so the 4 d-groups hit disjoint bank
// quarters. Row-sum via ones-MFMA; defer-max (THR=8, exp2 domain).
// ---------------------------------------------------------------------------
__global__ __launch_bounds__(256, 4) void attn_fwd(
    const u16* __restrict__ Qh, const u16* __restrict__ Kh,
    const u16* __restrict__ Vh, u16* __restrict__ attout)
{
    __shared__ u16 Ks[64 * 64];      // swizzled [kv][d]
    __shared__ u16 Vt[64 * 64];      // swizzled [d][kv]
    __shared__ u16 Pw[4 * 16 * 64];  // per-wave swizzled [q][kv]

    const int bid = blockIdx.x;
    const int pair = (bid >> 3) & 15;
    const int g = (bid & 7) + 8 * (bid >> 7);    // head-group: h + 16*b
    const int h = g & 15, b = g >> 4;

    const int tid = threadIdx.x, l = tid & 63, w = tid >> 6;
    const int fr = l & 15, fc = l >> 4;
    const int hb = b * 16 + h;
    const size_t head = (size_t)hb << 17;      // hb * 2048 * 64
    const u16* kb_g = Kh + head;
    const u16* vb_g = Vh + head;
    u16* pw = Pw + w * 1024;

    const int sw = (fr & 7) << 3;
    const int col0 = (fc * 8) ^ sw;
    const int col1 = col0 ^ 32;

    // reg-staging geometry: thread stages 32B of K row kr and V row kr
    const int kr = tid >> 2;               // 0..63
    const int kc0 = (tid & 3) * 16;        // u16 col of first 8-chunk
    const int kd0 = kc0 ^ ((kr & 7) << 3);
    const int kd1 = (kc0 + 8) ^ ((kr & 7) << 3);

    const float qs = 0.125f * 1.44269504f;  // 1/sqrt(64) * log2(e)

    bf16x8 onesv;
    #pragma unroll
    for (int j = 0; j < 8; ++j) onesv[j] = (__bf16)1.0f;

    #pragma unroll 1
    for (int half = 0; half < 2; ++half) {
        const int qt = half ? 31 - pair : pair;
        const int qbase = qt * 64 + w * 16;

        const u16* qp = Qh + head + (size_t)(qbase + fr) * 64 + fc * 8;
        bf16x8 qf0 = *(const bf16x8*)qp;
        bf16x8 qf1 = *(const bf16x8*)(qp + 32);
        #pragma unroll
        for (int j = 0; j < 8; ++j) {
            qf0[j] = (__bf16)((float)qf0[j] * qs);
            qf1[j] = (__bf16)((float)qf1[j] * qs);
        }

        f32x4 acc_o[4] = {};
        float m_run[4], l_run[4];
        #pragma unroll
        for (int j = 0; j < 4; ++j) { m_run[j] = -3.0e38f; l_run[j] = 0.0f; }

        const int nkt = qt + 1;
        // prologue: issue tile-0 loads
        ushort8v kA = *(const ushort8v*)(kb_g + (size_t)kr * 64 + kc0);
        ushort8v kB = *(const ushort8v*)(kb_g + (size_t)kr * 64 + kc0 + 8);
        ushort8v vA = *(const ushort8v*)(vb_g + (size_t)kr * 64 + kc0);
        ushort8v vB = *(const ushort8v*)(vb_g + (size_t)kr * 64 + kc0 + 8);

        #pragma unroll 1
        for (int kt = 0; kt < nkt; ++kt) {
            const int kv0 = kt * 64;
            const bool diag = (kt == qt);
            __syncthreads();            // all waves done reading prev tile LDS
            // ---- write staged K (b128, swizzled) ----
            *(ushort8v*)(Ks + kr * 64 + kd0) = kA;
            *(ushort8v*)(Ks + kr * 64 + kd1) = kB;
            // ---- write staged V transposed (scalar, bank-quarter swizzle) ----
            #pragma unroll
            for (int j = 0; j < 8; ++j) {
                const int d0 = kc0 + j, d1 = kc0 + 8 + j;
                Vt[d0 * 64 + (kr ^ ((d0 & 7) << 3) ^ ((d0 >> 4) << 4))] = vA[j];
                Vt[d1 * 64 + (kr ^ ((d1 & 7) << 3) ^ ((d1 >> 4) << 4))] = vB[j];
            }
            __syncthreads();            // tile ready
            // ---- issue next tile's loads (hidden under compute) ----
            if (kt + 1 < nkt) {
                const u16* kn = kb_g + (size_t)(kv0 + 64 + kr) * 64 + kc0;
                const u16* vn = vb_g + (size_t)(kv0 + 64 + kr) * 64 + kc0;
                kA = *(const ushort8v*)kn; kB = *(const ushort8v*)(kn + 8);
                vA = *(const ushort8v*)vn; vB = *(const ushort8v*)(vn + 8);
            }

            // ---- S = Q K^T : 4 n-blocks of 16 kv ----
            f32x4 sa[4] = {};
            __builtin_amdgcn_s_setprio(1);
            #pragma unroll
            for (int nb = 0; nb < 4; ++nb) {
                const u16* kb = Ks + (nb * 16 + fr) * 64;
                sa[nb] = __builtin_amdgcn_mfma_f32_16x16x32_bf16(
                    qf0, *(const bf16x8*)(kb + col0), sa[nb], 0, 0, 0);
                sa[nb] = __builtin_amdgcn_mfma_f32_16x16x32_bf16(
                    qf1, *(const bf16x8*)(kb + col1), sa[nb], 0, 0, 0);
            }
            __builtin_amdgcn_s_setprio(0);

            // ---- online softmax (exp2 domain, defer-max) ----
            float mx[4];
            #pragma unroll
            for (int j = 0; j < 4; ++j) {
                if (diag) {
                    const int qg = qbase + fc * 4 + j;
                    #pragma unroll
                    for (int nb = 0; nb < 4; ++nb) {
                        const int kg = kv0 + nb * 16 + fr;
                        if (kg > qg) sa[nb][j] = -3.0e38f;
                    }
                }
                mx[j] = fmaxf(fmaxf(sa[0][j], sa[1][j]), fmaxf(sa[2][j], sa[3][j]));
            }
            #pragma unroll
            for (int o = 1; o < 16; o <<= 1)
                #pragma unroll
                for (int j = 0; j < 4; ++j)
                    mx[j] = fmaxf(mx[j], __shfl_xor(mx[j], o));

            bool need = false;
            #pragma unroll
            for (int j = 0; j < 4; ++j)
                need = need || (mx[j] > m_run[j] + 8.0f);
            if (__any(need)) {
                float alpha[4];
                #pragma unroll
                for (int j = 0; j < 4; ++j) {
                    const float mn = fmaxf(m_run[j], mx[j]);
                    alpha[j] = exp2f(m_run[j] - mn);
                    m_run[j] = mn;
                    l_run[j] *= alpha[j];
                }
                #pragma unroll
                for (int db = 0; db < 4; ++db)
                    #pragma unroll
                    for (int j = 0; j < 4; ++j)
                        acc_o[db][j] *= alpha[j];
            }

            #pragma unroll
            for (int nb = 0; nb < 4; ++nb)
                #pragma unroll
                for (int j = 0; j < 4; ++j)
                    sa[nb][j] = exp2f(sa[nb][j] - m_run[j]);

            // ---- P -> per-wave LDS (same-wave ordering, no barrier), PV ----
            #pragma unroll
            for (int j = 0; j < 4; ++j) {
                const int q = fc * 4 + j;
                u16* prow = pw + q * 64;
                const int qx = (q & 7) << 3;
                #pragma unroll
                for (int nb = 0; nb < 4; ++nb)
                    prow[(nb * 16 + fr) ^ qx] = f2bf(sa[nb][j]);
            }
            const u16* prd = pw + fr * 64;
            const bf16x8 pf0 = *(const bf16x8*)(prd + col0);
            const bf16x8 pf1 = *(const bf16x8*)(prd + col1);
            f32x4 acc_s = {};
            __builtin_amdgcn_s_setprio(1);
            #pragma unroll
            for (int db = 0; db < 4; ++db) {
                const u16* vb = Vt + (db * 16 + fr) * 64;
                const int vx = db << 4;
                acc_o[db] = __builtin_amdgcn_mfma_f32_16x16x32_bf16(
                    pf0, *(const bf16x8*)(vb + (col0 ^ vx)), acc_o[db], 0, 0, 0);
                acc_o[db] = __builtin_amdgcn_mfma_f32_16x16x32_bf16(
                    pf1, *(const bf16x8*)(vb + (col1 ^ vx)), acc_o[db], 0, 0, 0);
            }
            acc_s = __builtin_amdgcn_mfma_f32_16x16x32_bf16(pf0, onesv, acc_s, 0, 0, 0);
            acc_s = __builtin_amdgcn_mfma_f32_16x16x32_bf16(pf1, onesv, acc_s, 0, 0, 0);
            __builtin_amdgcn_s_setprio(0);
            #pragma unroll
            for (int j = 0; j < 4; ++j)
                l_run[j] += acc_s[j];
        }

        float inv[4];
        #pragma unroll
        for (int j = 0; j < 4; ++j) inv[j] = 1.0f / l_run[j];
        const size_t bS = (size_t)b * 2048;
        #pragma unroll
        for (int db = 0; db < 4; ++db)
            #pragma unroll
            for (int j = 0; j < 4; ++j)
                attout[(bS + qbase + fc * 4 + j) * 1024 + h * 64 + db * 16 + fr] =
                    f2bf(acc_o[db][j] * inv[j]);
    }
}

// ---------------------------------------------------------------------------
extern "C" void kernel_launch(void* const* d_in, const int* in_sizes, int n_in,
                              void* d_out, int out_size, void* d_ws, size_t ws_size,
                              hipStream_t stream)
{
    const float* x    = (const float*)d_in[0];
    const float* Wq   = (const float*)d_in[1];
    const float* Wk   = (const float*)d_in[2];
    const float* Wv   = (const float*)d_in[3];
    const float* ln1g = (const float*)d_in[4];
    const float* ln1b = (const float*)d_in[5];
    const float* ln2g = (const float*)d_in[6];
    const float* ln2b = (const float*)d_in[7];
    const float* W1   = (const float*)d_in[8];
    const float* b1   = (const float*)d_in[9];
    const float* W2   = (const float*)d_in[10];
    const float* b2   = (const float*)d_in[11];

    char* ws = (char*)d_ws;
    u16*   wbf  = (u16*)(ws);                        // 5M bf16 = 10 MB
    u16*   xn   = (u16*)(ws + 10485760);             // 8M bf16 = 16 MB (reused as xt2)
    u16*   qkvb = (u16*)(ws + 27262976);             // 24M bf16 = 48 MB (reused as ffn hidden)
    u16*   attb = (u16*)(ws + 77594624);             // 8M bf16 = 16 MB
    float* xt   = (float*)(ws + 94371840);           // 8M fp32 = 32 MB

    cvt_w<<<1024, 256, 0, stream>>>(Wq, Wk, Wv, W1, W2, wbf);
    ln_kernel<false><<<8192, 256, 0, stream>>>(x, nullptr, ln1g, ln1b, nullptr, xn);
    gemm_bt<0><<<dim3(64, 24), 256, 0, stream>>>(xn, wbf, qkvb, nullptr, nullptr,
                                                 8192, 3072, 1024);
    attn_fwd<<<1024, 256, 0, stream>>>(qkvb, qkvb + 8388608, qkvb + 16777216, attb);
    ln_kernel<true><<<8192, 256, 0, stream>>>(x, attb, ln2g, ln2b, xt, xn);
    gemm_bt<1><<<dim3(64, 8), 256, 0, stream>>>(xn, wbf + (3 << 20), qkvb, b1, nullptr,
                                                8192, 1024, 1024);
    gemm_bt<2><<<dim3(64, 8), 256, 0, stream>>>(qkvb, wbf + (4 << 20), d_out, b2, xt,
                                                8192, 1024, 1024);
}

// Round 5
// 238.057 us; speedup vs baseline: 2.4126x; 1.1601x over previous
//
#include <hip/hip_runtime.h>
#include <hip/hip_bf16.h>

typedef unsigned short u16;
typedef unsigned int u32;
typedef __attribute__((ext_vector_type(8))) __bf16 bf16x8;
typedef __attribute__((ext_vector_type(4))) float f32x4;
typedef __attribute__((ext_vector_type(8))) unsigned short ushort8v;
typedef __attribute__((ext_vector_type(4))) unsigned short u16x4;
typedef __attribute__((ext_vector_type(2))) unsigned int u32x2;

#define DEV __device__ __forceinline__

DEV u16 f2bf(float f) {
    union { float f; unsigned int i; } u; u.f = f;
    unsigned int x = u.i;
    unsigned int r = (x + 0x7fffu + ((x >> 16) & 1u)) >> 16;
    return (u16)r;
}
DEV float bf2f(u16 h) {
    union { unsigned int i; float f; } u; u.i = ((unsigned int)h) << 16;
    return u.f;
}
DEV u32 cvt_pk_bf16(float lo, float hi) {
    u32 r;
    asm("v_cvt_pk_bf16_f32 %0, %1, %2" : "=v"(r) : "v"(lo), "v"(hi));
    return r;
}

// ---------------------------------------------------------------------------
// Weight conversion: pack [Wq;Wk;Wv] as [3072,1024] bf16, then W1, W2.
// ---------------------------------------------------------------------------
__global__ __launch_bounds__(256) void cvt_w(
    const float* __restrict__ wq, const float* __restrict__ wk,
    const float* __restrict__ wv, const float* __restrict__ w1,
    const float* __restrict__ w2, u16* __restrict__ dst)
{
    const int i = (blockIdx.x * 256 + threadIdx.x) * 4;
    if (i >= (1 << 20)) return;
    auto conv4 = [](float4 a) {
        u16x4 r; r[0] = f2bf(a.x); r[1] = f2bf(a.y); r[2] = f2bf(a.z); r[3] = f2bf(a.w);
        return r;
    };
    *(u16x4*)(dst + i)               = conv4(*(const float4*)(wq + i));
    *(u16x4*)(dst + (1 << 20) + i)   = conv4(*(const float4*)(wk + i));
    *(u16x4*)(dst + (2 << 20) + i)   = conv4(*(const float4*)(wv + i));
    *(u16x4*)(dst + (3 << 20) + i)   = conv4(*(const float4*)(w1 + i));
    *(u16x4*)(dst + (4 << 20) + i)   = conv4(*(const float4*)(w2 + i));
}

// ---------------------------------------------------------------------------
// Fused (optional residual-add) + LayerNorm. Row per block (1024 cols).
// ---------------------------------------------------------------------------
template<bool ADD>
__global__ __launch_bounds__(256) void ln_kernel(
    const float* __restrict__ xin, const u16* __restrict__ addbf,
    const float* __restrict__ g, const float* __restrict__ be,
    float* __restrict__ xt_out, u16* __restrict__ y_bf)
{
    const int row = blockIdx.x;
    const int tid = threadIdx.x;
    const size_t base = (size_t)row * 1024 + tid * 4;

    float4 xv = *(const float4*)(xin + base);
    float v[4] = {xv.x, xv.y, xv.z, xv.w};
    if (ADD) {
        u16x4 a = *(const u16x4*)(addbf + base);
        v[0] += bf2f(a[0]); v[1] += bf2f(a[1]); v[2] += bf2f(a[2]); v[3] += bf2f(a[3]);
        float4 o; o.x = v[0]; o.y = v[1]; o.z = v[2]; o.w = v[3];
        *(float4*)(xt_out + base) = o;
    }
    float s = 0.f, ss = 0.f;
    #pragma unroll
    for (int j = 0; j < 4; ++j) { s += v[j]; ss += v[j] * v[j]; }
    #pragma unroll
    for (int o = 32; o > 0; o >>= 1) { s += __shfl_xor(s, o); ss += __shfl_xor(ss, o); }
    __shared__ float red[8];
    const int w = tid >> 6;
    if ((tid & 63) == 0) { red[w * 2] = s; red[w * 2 + 1] = ss; }
    __syncthreads();
    s  = red[0] + red[2] + red[4] + red[6];
    ss = red[1] + red[3] + red[5] + red[7];
    const float mu = s * (1.0f / 1024.0f);
    const float var = ss * (1.0f / 1024.0f) - mu * mu;
    const float rstd = rsqrtf(var + 1e-5f);

    const int col = tid * 4;
    float4 gv = *(const float4*)(g + col);
    float4 bv = *(const float4*)(be + col);
    u16x4 o4;
    o4[0] = f2bf((v[0] - mu) * rstd * gv.x + bv.x);
    o4[1] = f2bf((v[1] - mu) * rstd * gv.y + bv.y);
    o4[2] = f2bf((v[2] - mu) * rstd * gv.z + bv.z);
    o4[3] = f2bf((v[3] - mu) * rstd * gv.w + bv.w);
    *(u16x4*)(y_bf + base) = o4;
}

// ---------------------------------------------------------------------------
// GEMM: C[M,N] = A[M,K] @ Bt[N,K]^T   (A, Bt bf16 row-major)
// 128x128 tile, BK=32, 4 waves (2x2), 4x4 16x16 frags per wave.
// EPI 0: scatter to per-head Q/K/V [B,H,S,64] bf16 regions (N=3072).
// EPI 1: +bias, relu, bf16. EPI 2: +bias +resid, fp32.
// ---------------------------------------------------------------------------
template<int EPI>
__global__ __launch_bounds__(256, 2) void gemm_bt(
    const u16* __restrict__ A, const u16* __restrict__ Bt,
    void* __restrict__ Cout, const float* __restrict__ bias,
    const float* __restrict__ resid, int M, int N, int K)
{
    __shared__ u16 As[128 * 32];
    __shared__ u16 Bs[128 * 32];
    const int tid = threadIdx.x;
    const int l = tid & 63;
    const int w = tid >> 6;
    const int wm = w >> 1, wn = w & 1;
    const int fr = l & 15, fc = l >> 4;
    const size_t rowA0 = (size_t)blockIdx.x * 128;
    const size_t rowB0 = (size_t)blockIdx.y * 128;

    f32x4 acc[4][4] = {};
    const int ldoff = fr * 32 + fc * 8;

    const int nkt = K >> 5;
    for (int kt = 0; kt < nkt; ++kt) {
        __syncthreads();
        const int k0 = kt << 5;
        #pragma unroll
        for (int p = 0; p < 2; ++p) {
            const int rr = p * 64 + w * 16 + (l >> 2);
            const int cc = (l & 3) * 8;
            const u16* ga = A  + (rowA0 + rr) * K + k0 + cc;
            const u16* gb = Bt + (rowB0 + rr) * K + k0 + cc;
            __builtin_amdgcn_global_load_lds(
                (const __attribute__((address_space(1))) void*)ga,
                (__attribute__((address_space(3))) void*)(As + (p * 64 + w * 16) * 32),
                16, 0, 0);
            __builtin_amdgcn_global_load_lds(
                (const __attribute__((address_space(1))) void*)gb,
                (__attribute__((address_space(3))) void*)(Bs + (p * 64 + w * 16) * 32),
                16, 0, 0);
        }
        __syncthreads();
        bf16x8 af[4], bfv[4];
        #pragma unroll
        for (int m = 0; m < 4; ++m)
            af[m] = *(const bf16x8*)(As + (wm * 64 + m * 16) * 32 + ldoff);
        #pragma unroll
        for (int n = 0; n < 4; ++n)
            bfv[n] = *(const bf16x8*)(Bs + (wn * 64 + n * 16) * 32 + ldoff);
        #pragma unroll
        for (int m = 0; m < 4; ++m)
            #pragma unroll
            for (int n = 0; n < 4; ++n)
                acc[m][n] = __builtin_amdgcn_mfma_f32_16x16x32_bf16(
                    af[m], bfv[n], acc[m][n], 0, 0, 0);
    }

    const int r0 = (int)rowA0 + wm * 64;
    const int c0 = (int)rowB0 + wn * 64;
    #pragma unroll
    for (int m = 0; m < 4; ++m) {
        #pragma unroll
        for (int n = 0; n < 4; ++n) {
            const int row = r0 + m * 16 + fc * 4;
            const int col = c0 + n * 16 + fr;
            #pragma unroll
            for (int j = 0; j < 4; ++j) {
                float v = acc[m][n][j];
                if constexpr (EPI == 0) {
                    const int rowj = row + j;
                    const int which = col >> 10;          // 0=Q 1=K 2=V
                    const int hh = (col >> 6) & 15;
                    const int dd = col & 63;
                    const size_t dst = (size_t)which * 8388608 +
                        ((((size_t)(rowj >> 11) * 16 + hh) * 2048 + (rowj & 2047)) * 64 + dd);
                    ((u16*)Cout)[dst] = f2bf(v);
                } else if constexpr (EPI == 1) {
                    const size_t idx = (size_t)(row + j) * N + col;
                    v += bias[col];
                    v = fmaxf(v, 0.0f);
                    ((u16*)Cout)[idx] = f2bf(v);
                } else {
                    const size_t idx = (size_t)(row + j) * N + col;
                    v += bias[col] + resid[idx];
                    ((float*)Cout)[idx] = v;
                }
            }
        }
    }
}

// ---------------------------------------------------------------------------
// Causal flash attention, swapped-QK in-register softmax.
// Per-head Q/K/V in [B*H, S, 64] bf16. 1-D grid of 1024; decode puts all
// 16 pair-blocks of one (h,b) on the same XCD. Block processes q-tiles
// {pair, 31-pair} -> uniform 33 kv-tiles. 4 waves x 16 q-rows, KV tiles
// of 64. S^T = mfma(K,Q): lane owns its q-row (col=lane&15) -> row-max is
// 15 fmax + 2 bperm; m_run per-lane scalar; P packed via v_cvt_pk_bf16 and
// written as 4 ds_write_b64 (swizzled), read back as A-frag b128.
// Row-sum via ones-MFMA; defer-max (THR=8, exp2 domain).
// ---------------------------------------------------------------------------
__global__ __launch_bounds__(256, 4) void attn_fwd(
    const u16* __restrict__ Qh, const u16* __restrict__ Kh,
    const u16* __restrict__ Vh, u16* __restrict__ attout)
{
    __shared__ u16 Ks[64 * 64];      // swizzled [kv][d]
    __shared__ u16 Vt[64 * 64];      // swizzled [d][kv]
    __shared__ u16 Pw[4 * 16 * 64];  // per-wave swizzled [q][kv]

    const int bid = blockIdx.x;
    const int pair = (bid >> 3) & 15;
    const int g = (bid & 7) + 8 * (bid >> 7);    // head-group: h + 16*b
    const int h = g & 15, b = g >> 4;

    const int tid = threadIdx.x, l = tid & 63, w = tid >> 6;
    const int fr = l & 15, fc = l >> 4;
    const int hb = b * 16 + h;
    const size_t head = (size_t)hb << 17;      // hb * 2048 * 64
    const u16* kb_g = Kh + head;
    const u16* vb_g = Vh + head;
    u16* pw = Pw + w * 1024;

    const int sw = (fr & 7) << 3;
    const int col0 = (fc * 8) ^ sw;
    const int col1 = col0 ^ 32;

    // reg-staging geometry: thread stages 32B of K row kr and V row kr
    const int kr = tid >> 2;               // 0..63
    const int kc0 = (tid & 3) * 16;        // u16 col of first 8-chunk
    const int kd0 = kc0 ^ ((kr & 7) << 3);
    const int kd1 = (kc0 + 8) ^ ((kr & 7) << 3);

    const float qs = 0.125f * 1.44269504f;  // 1/sqrt(64) * log2(e)

    bf16x8 onesv;
    #pragma unroll
    for (int j = 0; j < 8; ++j) onesv[j] = (__bf16)1.0f;

    #pragma unroll 1
    for (int half = 0; half < 2; ++half) {
        const int qt = half ? 31 - pair : pair;
        const int qbase = qt * 64 + w * 16;
        const int qg = qbase + fr;          // this lane's q-row (swapped layout)

        const u16* qp = Qh + head + (size_t)(qbase + fr) * 64 + fc * 8;
        bf16x8 qf0 = *(const bf16x8*)qp;
        bf16x8 qf1 = *(const bf16x8*)(qp + 32);
        #pragma unroll
        for (int j = 0; j < 8; ++j) {
            qf0[j] = (__bf16)((float)qf0[j] * qs);
            qf1[j] = (__bf16)((float)qf1[j] * qs);
        }

        f32x4 acc_o[4] = {};
        float m_run = -3.0e38f;
        float l_run[4] = {0.f, 0.f, 0.f, 0.f};

        const int nkt = qt + 1;
        // prologue: issue tile-0 loads
        ushort8v kA = *(const ushort8v*)(kb_g + (size_t)kr * 64 + kc0);
        ushort8v kB = *(const ushort8v*)(kb_g + (size_t)kr * 64 + kc0 + 8);
        ushort8v vA = *(const ushort8v*)(vb_g + (size_t)kr * 64 + kc0);
        ushort8v vB = *(const ushort8v*)(vb_g + (size_t)kr * 64 + kc0 + 8);

        #pragma unroll 1
        for (int kt = 0; kt < nkt; ++kt) {
            const int kv0 = kt * 64;
            const bool diag = (kt == qt);
            __syncthreads();            // all waves done reading prev tile LDS
            // ---- write staged K (b128, swizzled) ----
            *(ushort8v*)(Ks + kr * 64 + kd0) = kA;
            *(ushort8v*)(Ks + kr * 64 + kd1) = kB;
            // ---- write staged V transposed (scalar, bank-quarter swizzle) ----
            #pragma unroll
            for (int j = 0; j < 8; ++j) {
                const int d0 = kc0 + j, d1 = kc0 + 8 + j;
                Vt[d0 * 64 + (kr ^ ((d0 & 7) << 3) ^ ((d0 >> 4) << 4))] = vA[j];
                Vt[d1 * 64 + (kr ^ ((d1 & 7) << 3) ^ ((d1 >> 4) << 4))] = vB[j];
            }
            __syncthreads();            // tile ready
            // ---- issue next tile's loads (hidden under compute) ----
            if (kt + 1 < nkt) {
                const u16* kn = kb_g + (size_t)(kv0 + 64 + kr) * 64 + kc0;
                const u16* vn = vb_g + (size_t)(kv0 + 64 + kr) * 64 + kc0;
                kA = *(const ushort8v*)kn; kB = *(const ushort8v*)(kn + 8);
                vA = *(const ushort8v*)vn; vB = *(const ushort8v*)(vn + 8);
            }

            // ---- S^T = K Q^T : lane owns q-row qg, kv = kv0+nb*16+fc*4+j ----
            f32x4 sa[4] = {};
            __builtin_amdgcn_s_setprio(1);
            #pragma unroll
            for (int nb = 0; nb < 4; ++nb) {
                const u16* kb = Ks + (nb * 16 + fr) * 64;
                sa[nb] = __builtin_amdgcn_mfma_f32_16x16x32_bf16(
                    *(const bf16x8*)(kb + col0), qf0, sa[nb], 0, 0, 0);
                sa[nb] = __builtin_amdgcn_mfma_f32_16x16x32_bf16(
                    *(const bf16x8*)(kb + col1), qf1, sa[nb], 0, 0, 0);
            }
            __builtin_amdgcn_s_setprio(0);

            // ---- causal mask (diag tile only) ----
            if (diag) {
                #pragma unroll
                for (int nb = 0; nb < 4; ++nb)
                    #pragma unroll
                    for (int j = 0; j < 4; ++j) {
                        const int kg = kv0 + nb * 16 + fc * 4 + j;
                        if (kg > qg) sa[nb][j] = -3.0e38f;
                    }
            }

            // ---- row max: 16 in-register values + cross-fc reduce ----
            float mx = sa[0][0];
            #pragma unroll
            for (int nb = 0; nb < 4; ++nb)
                #pragma unroll
                for (int j = 0; j < 4; ++j)
                    mx = fmaxf(mx, sa[nb][j]);
            mx = fmaxf(mx, __shfl_xor(mx, 16));
            mx = fmaxf(mx, __shfl_xor(mx, 32));

            // ---- defer-max rescale ----
            if (__any(mx > m_run + 8.0f)) {
                const float mn = fmaxf(m_run, mx);
                const float alpha = exp2f(m_run - mn);
                m_run = mn;
                float aj[4];
                #pragma unroll
                for (int j = 0; j < 4; ++j)
                    aj[j] = __shfl(alpha, fc * 4 + j);
                #pragma unroll
                for (int j = 0; j < 4; ++j)
                    l_run[j] *= aj[j];
                #pragma unroll
                for (int db = 0; db < 4; ++db)
                    #pragma unroll
                    for (int j = 0; j < 4; ++j)
                        acc_o[db][j] *= aj[j];
            }

            #pragma unroll
            for (int nb = 0; nb < 4; ++nb)
                #pragma unroll
                for (int j = 0; j < 4; ++j)
                    sa[nb][j] = exp2f(sa[nb][j] - m_run);

            // ---- P -> per-wave LDS: pack pairs, 4 x ds_write_b64 ----
            #pragma unroll
            for (int nb = 0; nb < 4; ++nb) {
                u32x2 pkv;
                pkv[0] = cvt_pk_bf16(sa[nb][0], sa[nb][1]);
                pkv[1] = cvt_pk_bf16(sa[nb][2], sa[nb][3]);
                *(u32x2*)(pw + fr * 64 + ((nb * 16 + fc * 4) ^ sw)) = pkv;
            }
            const u16* prd = pw + fr * 64;
            const bf16x8 pf0 = *(const bf16x8*)(prd + col0);
            const bf16x8 pf1 = *(const bf16x8*)(prd + col1);
            f32x4 acc_s = {};
            __builtin_amdgcn_s_setprio(1);
            #pragma unroll
            for (int db = 0; db < 4; ++db) {
                const u16* vb = Vt + (db * 16 + fr) * 64;
                const int vx = db << 4;
                acc_o[db] = __builtin_amdgcn_mfma_f32_16x16x32_bf16(
                    pf0, *(const bf16x8*)(vb + (col0 ^ vx)), acc_o[db], 0, 0, 0);
                acc_o[db] = __builtin_amdgcn_mfma_f32_16x16x32_bf16(
                    pf1, *(const bf16x8*)(vb + (col1 ^ vx)), acc_o[db], 0, 0, 0);
            }
            acc_s = __builtin_amdgcn_mfma_f32_16x16x32_bf16(pf0, onesv, acc_s, 0, 0, 0);
            acc_s = __builtin_amdgcn_mfma_f32_16x16x32_bf16(pf1, onesv, acc_s, 0, 0, 0);
            __builtin_amdgcn_s_setprio(0);
            #pragma unroll
            for (int j = 0; j < 4; ++j)
                l_run[j] += acc_s[j];
        }

        float inv[4];
        #pragma unroll
        for (int j = 0; j < 4; ++j) inv[j] = 1.0f / l_run[j];
        const size_t bS = (size_t)b * 2048;
        #pragma unroll
        for (int db = 0; db < 4; ++db)
            #pragma unroll
            for (int j = 0; j < 4; ++j)
                attout[(bS + qbase + fc * 4 + j) * 1024 + h * 64 + db * 16 + fr] =
                    f2bf(acc_o[db][j] * inv[j]);
    }
}

// ---------------------------------------------------------------------------
extern "C" void kernel_launch(void* const* d_in, const int* in_sizes, int n_in,
                              void* d_out, int out_size, void* d_ws, size_t ws_size,
                              hipStream_t stream)
{
    const float* x    = (const float*)d_in[0];
    const float* Wq   = (const float*)d_in[1];
    const float* Wk   = (const float*)d_in[2];
    const float* Wv   = (const float*)d_in[3];
    const float* ln1g = (const float*)d_in[4];
    const float* ln1b = (const float*)d_in[5];
    const float* ln2g = (const float*)d_in[6];
    const float* ln2b = (const float*)d_in[7];
    const float* W1   = (const float*)d_in[8];
    const float* b1   = (const float*)d_in[9];
    const float* W2   = (const float*)d_in[10];
    const float* b2   = (const float*)d_in[11];

    char* ws = (char*)d_ws;
    u16*   wbf  = (u16*)(ws);                        // 5M bf16 = 10 MB
    u16*   xn   = (u16*)(ws + 10485760);             // 8M bf16 = 16 MB (reused as xt2)
    u16*   qkvb = (u16*)(ws + 27262976);             // 24M bf16 = 48 MB (reused as ffn hidden)
    u16*   attb = (u16*)(ws + 77594624);             // 8M bf16 = 16 MB
    float* xt   = (float*)(ws + 94371840);           // 8M fp32 = 32 MB

    cvt_w<<<1024, 256, 0, stream>>>(Wq, Wk, Wv, W1, W2, wbf);
    ln_kernel<false><<<8192, 256, 0, stream>>>(x, nullptr, ln1g, ln1b, nullptr, xn);
    gemm_bt<0><<<dim3(64, 24), 256, 0, stream>>>(xn, wbf, qkvb, nullptr, nullptr,
                                                 8192, 3072, 1024);
    attn_fwd<<<1024, 256, 0, stream>>>(qkvb, qkvb + 8388608, qkvb + 16777216, attb);
    ln_kernel<true><<<8192, 256, 0, stream>>>(x, attb, ln2g, ln2b, xt, xn);
    gemm_bt<1><<<dim3(64, 8), 256, 0, stream>>>(xn, wbf + (3 << 20), qkvb, b1, nullptr,
                                                8192, 1024, 1024);
    gemm_bt<2><<<dim3(64, 8), 256, 0, stream>>>(qkvb, wbf + (4 << 20), d_out, b2, xt,
                                                8192, 1024, 1024);
}

// Round 6
// 227.729 us; speedup vs baseline: 2.5220x; 1.0454x over previous
//
#include <hip/hip_runtime.h>
#include <hip/hip_bf16.h>

typedef unsigned short u16;
typedef unsigned int u32;
typedef __attribute__((ext_vector_type(8))) __bf16 bf16x8;
typedef __attribute__((ext_vector_type(4))) float f32x4;
typedef __attribute__((ext_vector_type(8))) unsigned short ushort8v;
typedef __attribute__((ext_vector_type(4))) unsigned short u16x4;
typedef __attribute__((ext_vector_type(2))) unsigned int u32x2;

#define DEV __device__ __forceinline__
#define AS1 __attribute__((address_space(1)))
#define AS3 __attribute__((address_space(3)))

DEV u16 f2bf(float f) {
    union { float f; unsigned int i; } u; u.f = f;
    unsigned int x = u.i;
    unsigned int r = (x + 0x7fffu + ((x >> 16) & 1u)) >> 16;
    return (u16)r;
}
DEV float bf2f(u16 h) {
    union { unsigned int i; float f; } u; u.i = ((unsigned int)h) << 16;
    return u.f;
}
DEV u32 cvt_pk_bf16(float lo, float hi) {
    u32 r;
    asm("v_cvt_pk_bf16_f32 %0, %1, %2" : "=v"(r) : "v"(lo), "v"(hi));
    return r;
}

// ---------------------------------------------------------------------------
// Weight conversion: pack [Wq;Wk;Wv] as [3072,1024] bf16, then W1, W2.
// ---------------------------------------------------------------------------
__global__ __launch_bounds__(256) void cvt_w(
    const float* __restrict__ wq, const float* __restrict__ wk,
    const float* __restrict__ wv, const float* __restrict__ w1,
    const float* __restrict__ w2, u16* __restrict__ dst)
{
    const int i = (blockIdx.x * 256 + threadIdx.x) * 4;
    if (i >= (1 << 20)) return;
    auto conv4 = [](float4 a) {
        u16x4 r; r[0] = f2bf(a.x); r[1] = f2bf(a.y); r[2] = f2bf(a.z); r[3] = f2bf(a.w);
        return r;
    };
    *(u16x4*)(dst + i)               = conv4(*(const float4*)(wq + i));
    *(u16x4*)(dst + (1 << 20) + i)   = conv4(*(const float4*)(wk + i));
    *(u16x4*)(dst + (2 << 20) + i)   = conv4(*(const float4*)(wv + i));
    *(u16x4*)(dst + (3 << 20) + i)   = conv4(*(const float4*)(w1 + i));
    *(u16x4*)(dst + (4 << 20) + i)   = conv4(*(const float4*)(w2 + i));
}

// ---------------------------------------------------------------------------
// Fused (optional residual-add) + LayerNorm. Row per block (1024 cols).
// ---------------------------------------------------------------------------
template<bool ADD>
__global__ __launch_bounds__(256) void ln_kernel(
    const float* __restrict__ xin, const u16* __restrict__ addbf,
    const float* __restrict__ g, const float* __restrict__ be,
    float* __restrict__ xt_out, u16* __restrict__ y_bf)
{
    const int row = blockIdx.x;
    const int tid = threadIdx.x;
    const size_t base = (size_t)row * 1024 + tid * 4;

    float4 xv = *(const float4*)(xin + base);
    float v[4] = {xv.x, xv.y, xv.z, xv.w};
    if (ADD) {
        u16x4 a = *(const u16x4*)(addbf + base);
        v[0] += bf2f(a[0]); v[1] += bf2f(a[1]); v[2] += bf2f(a[2]); v[3] += bf2f(a[3]);
        float4 o; o.x = v[0]; o.y = v[1]; o.z = v[2]; o.w = v[3];
        *(float4*)(xt_out + base) = o;
    }
    float s = 0.f, ss = 0.f;
    #pragma unroll
    for (int j = 0; j < 4; ++j) { s += v[j]; ss += v[j] * v[j]; }
    #pragma unroll
    for (int o = 32; o > 0; o >>= 1) { s += __shfl_xor(s, o); ss += __shfl_xor(ss, o); }
    __shared__ float red[8];
    const int w = tid >> 6;
    if ((tid & 63) == 0) { red[w * 2] = s; red[w * 2 + 1] = ss; }
    __syncthreads();
    s  = red[0] + red[2] + red[4] + red[6];
    ss = red[1] + red[3] + red[5] + red[7];
    const float mu = s * (1.0f / 1024.0f);
    const float var = ss * (1.0f / 1024.0f) - mu * mu;
    const float rstd = rsqrtf(var + 1e-5f);

    const int col = tid * 4;
    float4 gv = *(const float4*)(g + col);
    float4 bv = *(const float4*)(be + col);
    u16x4 o4;
    o4[0] = f2bf((v[0] - mu) * rstd * gv.x + bv.x);
    o4[1] = f2bf((v[1] - mu) * rstd * gv.y + bv.y);
    o4[2] = f2bf((v[2] - mu) * rstd * gv.z + bv.z);
    o4[3] = f2bf((v[3] - mu) * rstd * gv.w + bv.w);
    *(u16x4*)(y_bf + base) = o4;
}

// ---------------------------------------------------------------------------
// GEMM: C[M,N] = A[M,K] @ Bt[N,K]^T   (A, Bt bf16 row-major)
// 128x128 tile, BK=64 as two K=32 panels ([2][128][32] LDS, linear dest +
// permuted global source), 4 waves (2x2), 4x4 16x16 frags per wave.
// EPI 0: scatter to per-head Q/K/V [B,H,S,64] bf16 regions (N=3072).
// EPI 1: +bias, relu, bf16. EPI 2: +bias +resid, fp32.
// ---------------------------------------------------------------------------
template<int EPI>
__global__ __launch_bounds__(256, 2) void gemm_bt(
    const u16* __restrict__ A, const u16* __restrict__ Bt,
    void* __restrict__ Cout, const float* __restrict__ bias,
    const float* __restrict__ resid, int M, int N, int K)
{
    __shared__ u16 As[2 * 128 * 32];
    __shared__ u16 Bs[2 * 128 * 32];
    const int tid = threadIdx.x;
    const int l = tid & 63;
    const int w = tid >> 6;
    const int wm = w >> 1, wn = w & 1;
    const int fr = l & 15, fc = l >> 4;
    const size_t rowA0 = (size_t)blockIdx.x * 128;
    const size_t rowB0 = (size_t)blockIdx.y * 128;

    f32x4 acc[4][4] = {};
    const int ldoff = fr * 32 + fc * 8;

    const int nkt = K >> 6;
    for (int kt = 0; kt < nkt; ++kt) {
        __syncthreads();
        const int k0 = kt << 6;
        #pragma unroll
        for (int q = 0; q < 4; ++q) {
            // dest elem = q*2048 + w*512 + l*8 (linear); decode:
            //   panel = q>>1, row = (q&1)*64 + w*16 + (l>>2), kk = (l&3)*8
            const int row = (q & 1) * 64 + w * 16 + (l >> 2);
            const int kk  = (q >> 1) * 32 + (l & 3) * 8;
            const u16* ga = A  + (rowA0 + row) * K + k0 + kk;
            const u16* gb = Bt + (rowB0 + row) * K + k0 + kk;
            u16* da = As + q * 2048 + w * 512;
            u16* db = Bs + q * 2048 + w * 512;
            __builtin_amdgcn_global_load_lds((const AS1 void*)ga, (AS3 void*)da, 16, 0, 0);
            __builtin_amdgcn_global_load_lds((const AS1 void*)gb, (AS3 void*)db, 16, 0, 0);
        }
        __syncthreads();
        #pragma unroll
        for (int ks = 0; ks < 2; ++ks) {
            const u16* as_p = As + ks * 4096;
            const u16* bs_p = Bs + ks * 4096;
            bf16x8 af[4], bfv[4];
            #pragma unroll
            for (int m = 0; m < 4; ++m)
                af[m] = *(const bf16x8*)(as_p + (wm * 64 + m * 16) * 32 + ldoff);
            #pragma unroll
            for (int n = 0; n < 4; ++n)
                bfv[n] = *(const bf16x8*)(bs_p + (wn * 64 + n * 16) * 32 + ldoff);
            #pragma unroll
            for (int m = 0; m < 4; ++m)
                #pragma unroll
                for (int n = 0; n < 4; ++n)
                    acc[m][n] = __builtin_amdgcn_mfma_f32_16x16x32_bf16(
                        af[m], bfv[n], acc[m][n], 0, 0, 0);
        }
    }

    const int r0 = (int)rowA0 + wm * 64;
    const int c0 = (int)rowB0 + wn * 64;
    #pragma unroll
    for (int m = 0; m < 4; ++m) {
        #pragma unroll
        for (int n = 0; n < 4; ++n) {
            const int row = r0 + m * 16 + fc * 4;
            const int col = c0 + n * 16 + fr;
            #pragma unroll
            for (int j = 0; j < 4; ++j) {
                float v = acc[m][n][j];
                if constexpr (EPI == 0) {
                    const int rowj = row + j;
                    const int which = col >> 10;          // 0=Q 1=K 2=V
                    const int hh = (col >> 6) & 15;
                    const int dd = col & 63;
                    const size_t dst = (size_t)which * 8388608 +
                        ((((size_t)(rowj >> 11) * 16 + hh) * 2048 + (rowj & 2047)) * 64 + dd);
                    ((u16*)Cout)[dst] = f2bf(v);
                } else if constexpr (EPI == 1) {
                    const size_t idx = (size_t)(row + j) * N + col;
                    v += bias[col];
                    v = fmaxf(v, 0.0f);
                    ((u16*)Cout)[idx] = f2bf(v);
                } else {
                    const size_t idx = (size_t)(row + j) * N + col;
                    v += bias[col] + resid[idx];
                    ((float*)Cout)[idx] = v;
                }
            }
        }
    }
}

// ---------------------------------------------------------------------------
// Causal flash attention: swapped-QK in-reg softmax + single-barrier dbuf.
// Per-head Q/K/V in [B*H, S, 64] bf16. 1024 blocks; XCD-colocated decode.
// Block does q-tiles {pair, 31-pair} (33 kv-tiles). 4 waves x 16 q-rows,
// KV tile 64. K staged via global_load_lds (pre-swizzled source); V reg-
// staged 2-deep, transposed+swizzled scalar writes after compute. ONE raw
// s_barrier per tile, counted vmcnt (loads stay in flight across barrier).
// ---------------------------------------------------------------------------
__global__ __launch_bounds__(256, 4) void attn_fwd(
    const u16* __restrict__ Qh, const u16* __restrict__ Kh,
    const u16* __restrict__ Vh, u16* __restrict__ attout)
{
    __shared__ u16 Ks[2][64 * 64];   // swizzled [kv][d]
    __shared__ u16 Vt[2][64 * 64];   // swizzled [d][kv]
    __shared__ u16 Pw[4 * 16 * 64];  // per-wave swizzled [q][kv]

    const int bid = blockIdx.x;
    const int pair = (bid >> 3) & 15;
    const int g = (bid & 7) + 8 * (bid >> 7);    // head-group: h + 16*b
    const int h = g & 15, b = g >> 4;

    const int tid = threadIdx.x, l = tid & 63, w = tid >> 6;
    const int fr = l & 15, fc = l >> 4;
    const int hb = b * 16 + h;
    const size_t head = (size_t)hb << 17;      // hb * 2048 * 64
    const u16* kb_g = Kh + head;
    const u16* vb_g = Vh + head;
    u16* pw = Pw + w * 1024;

    const int sw = (fr & 7) << 3;
    const int col0 = (fc * 8) ^ sw;
    const int col1 = col0 ^ 32;

    // K gload geometry: issue i covers rows w*16+i*8 .. +8, lane: row += l>>3,
    // col chunk (l&7)*8, source col pre-swizzled by row&7 == l>>3.
    const int krow0 = w * 16 + (l >> 3);
    const int kdsw  = ((l & 7) * 8) ^ ((l >> 3) << 3);

    // V reg-stage geometry: thread stages 32B of V row kr.
    const int kr = tid >> 2;
    const int kc0 = (tid & 3) * 16;

    const float qs = 0.125f * 1.44269504f;  // 1/sqrt(64) * log2(e)

    bf16x8 onesv;
    #pragma unroll
    for (int j = 0; j < 8; ++j) onesv[j] = (__bf16)1.0f;

    #pragma unroll 1
    for (int half = 0; half < 2; ++half) {
        const int qt = half ? 31 - pair : pair;
        const int qbase = qt * 64 + w * 16;
        const int qg = qbase + fr;          // this lane's q-row (swapped layout)

        const u16* qp = Qh + head + (size_t)(qbase + fr) * 64 + fc * 8;
        bf16x8 qf0 = *(const bf16x8*)qp;
        bf16x8 qf1 = *(const bf16x8*)(qp + 32);
        #pragma unroll
        for (int j = 0; j < 8; ++j) {
            qf0[j] = (__bf16)((float)qf0[j] * qs);
            qf1[j] = (__bf16)((float)qf1[j] * qs);
        }

        f32x4 acc_o[4] = {};
        float m_run = -3.0e38f;
        float l_run[4] = {0.f, 0.f, 0.f, 0.f};

        const int nkt = qt + 1;
        int cur = 0;

        // ---- prologue: K0 -> Ks[0] (gload), V0 -> Vt[0], issue V1 ----
        #pragma unroll
        for (int i = 0; i < 2; ++i) {
            const int row = krow0 + i * 8;
            __builtin_amdgcn_global_load_lds(
                (const AS1 void*)(kb_g + (size_t)row * 64 + kdsw),
                (AS3 void*)(&Ks[0][0] + (w * 16 + i * 8) * 64), 16, 0, 0);
        }
        __builtin_amdgcn_sched_barrier(0);
        {
            ushort8v v0a = *(const ushort8v*)(vb_g + (size_t)kr * 64 + kc0);
            ushort8v v0b = *(const ushort8v*)(vb_g + (size_t)kr * 64 + kc0 + 8);
            #pragma unroll
            for (int j = 0; j < 8; ++j) {
                const int d0 = kc0 + j, d1 = kc0 + 8 + j;
                Vt[0][d0 * 64 + (kr ^ ((d0 & 7) << 3) ^ ((d0 >> 4) << 4))] = v0a[j];
                Vt[0][d1 * 64 + (kr ^ ((d1 & 7) << 3) ^ ((d1 >> 4) << 4))] = v0b[j];
            }
        }
        ushort8v vA, vB;
        if (nkt > 1) {
            vA = *(const ushort8v*)(vb_g + (size_t)(64 + kr) * 64 + kc0);
            vB = *(const ushort8v*)(vb_g + (size_t)(64 + kr) * 64 + kc0 + 8);
        }
        __builtin_amdgcn_sched_barrier(0);
        if (nkt > 1) asm volatile("s_waitcnt vmcnt(2)" ::: "memory");
        else         asm volatile("s_waitcnt vmcnt(0)" ::: "memory");
        asm volatile("s_waitcnt lgkmcnt(0)" ::: "memory");
        __builtin_amdgcn_s_barrier();

        #pragma unroll 1
        for (int kt = 0; kt < nkt; ++kt) {
            const int kv0 = kt * 64;
            const bool diag = (kt == qt);
            const u16* ksc = &Ks[cur][0];
            const u16* vtc = &Vt[cur][0];

            // ---- 1) issue K(kt+1) -> Ks[cur^1] ----
            if (kt + 1 < nkt) {
                u16* ksn = &Ks[cur ^ 1][0];
                #pragma unroll
                for (int i = 0; i < 2; ++i) {
                    const int row = krow0 + i * 8;
                    __builtin_amdgcn_global_load_lds(
                        (const AS1 void*)(kb_g + (size_t)(kv0 + 64 + row) * 64 + kdsw),
                        (AS3 void*)(ksn + (w * 16 + i * 8) * 64), 16, 0, 0);
                }
            }
            __builtin_amdgcn_sched_barrier(0);

            // ---- 2) compute tile kt ----
            f32x4 sa[4] = {};
            __builtin_amdgcn_s_setprio(1);
            #pragma unroll
            for (int nb = 0; nb < 4; ++nb) {
                const u16* kb = ksc + (nb * 16 + fr) * 64;
                sa[nb] = __builtin_amdgcn_mfma_f32_16x16x32_bf16(
                    *(const bf16x8*)(kb + col0), qf0, sa[nb], 0, 0, 0);
                sa[nb] = __builtin_amdgcn_mfma_f32_16x16x32_bf16(
                    *(const bf16x8*)(kb + col1), qf1, sa[nb], 0, 0, 0);
            }
            __builtin_amdgcn_s_setprio(0);

            if (diag) {
                #pragma unroll
                for (int nb = 0; nb < 4; ++nb)
                    #pragma unroll
                    for (int j = 0; j < 4; ++j) {
                        const int kg = kv0 + nb * 16 + fc * 4 + j;
                        if (kg > qg) sa[nb][j] = -3.0e38f;
                    }
            }

            float mx = sa[0][0];
            #pragma unroll
            for (int nb = 0; nb < 4; ++nb)
                #pragma unroll
                for (int j = 0; j < 4; ++j)
                    mx = fmaxf(mx, sa[nb][j]);
            mx = fmaxf(mx, __shfl_xor(mx, 16));
            mx = fmaxf(mx, __shfl_xor(mx, 32));

            if (__any(mx > m_run + 8.0f)) {
                const float mn = fmaxf(m_run, mx);
                const float alpha = exp2f(m_run - mn);
                m_run = mn;
                float aj[4];
                #pragma unroll
                for (int j = 0; j < 4; ++j)
                    aj[j] = __shfl(alpha, fc * 4 + j);
                #pragma unroll
                for (int j = 0; j < 4; ++j)
                    l_run[j] *= aj[j];
                #pragma unroll
                for (int db = 0; db < 4; ++db)
                    #pragma unroll
                    for (int j = 0; j < 4; ++j)
                        acc_o[db][j] *= aj[j];
            }

            #pragma unroll
            for (int nb = 0; nb < 4; ++nb)
                #pragma unroll
                for (int j = 0; j < 4; ++j)
                    sa[nb][j] = exp2f(sa[nb][j] - m_run);

            // P -> per-wave LDS (packed b64, same-wave round trip)
            #pragma unroll
            for (int nb = 0; nb < 4; ++nb) {
                u32x2 pkv;
                pkv[0] = cvt_pk_bf16(sa[nb][0], sa[nb][1]);
                pkv[1] = cvt_pk_bf16(sa[nb][2], sa[nb][3]);
                *(u32x2*)(pw + fr * 64 + ((nb * 16 + fc * 4) ^ sw)) = pkv;
            }
            const u16* prd = pw + fr * 64;
            const bf16x8 pf0 = *(const bf16x8*)(prd + col0);
            const bf16x8 pf1 = *(const bf16x8*)(prd + col1);
            f32x4 acc_s = {};
            __builtin_amdgcn_s_setprio(1);
            #pragma unroll
            for (int db = 0; db < 4; ++db) {
                const u16* vb = vtc + (db * 16 + fr) * 64;
                const int vx = db << 4;
                acc_o[db] = __builtin_amdgcn_mfma_f32_16x16x32_bf16(
                    pf0, *(const bf16x8*)(vb + (col0 ^ vx)), acc_o[db], 0, 0, 0);
                acc_o[db] = __builtin_amdgcn_mfma_f32_16x16x32_bf16(
                    pf1, *(const bf16x8*)(vb + (col1 ^ vx)), acc_o[db], 0, 0, 0);
            }
            acc_s = __builtin_amdgcn_mfma_f32_16x16x32_bf16(pf0, onesv, acc_s, 0, 0, 0);
            acc_s = __builtin_amdgcn_mfma_f32_16x16x32_bf16(pf1, onesv, acc_s, 0, 0, 0);
            __builtin_amdgcn_s_setprio(0);
            #pragma unroll
            for (int j = 0; j < 4; ++j)
                l_run[j] += acc_s[j];

            // ---- 4) write V(kt+1) regs -> Vt[cur^1] (compiler waits vA/vB) ----
            if (kt + 1 < nkt) {
                u16* vtn = &Vt[cur ^ 1][0];
                #pragma unroll
                for (int j = 0; j < 8; ++j) {
                    const int d0 = kc0 + j, d1 = kc0 + 8 + j;
                    vtn[d0 * 64 + (kr ^ ((d0 & 7) << 3) ^ ((d0 >> 4) << 4))] = vA[j];
                    vtn[d1 * 64 + (kr ^ ((d1 & 7) << 3) ^ ((d1 >> 4) << 4))] = vB[j];
                }
            }
            // ---- 5) issue V(kt+2) loads ----
            if (kt + 2 < nkt) {
                const u16* vn = vb_g + (size_t)(kv0 + 128 + kr) * 64 + kc0;
                vA = *(const ushort8v*)vn;
                vB = *(const ushort8v*)(vn + 8);
            }
            __builtin_amdgcn_sched_barrier(0);
            // ---- 6) counted drain: K(kt+1) landed; V(kt+2) stays in flight ----
            if (kt + 1 < nkt) {
                if (kt + 2 < nkt) asm volatile("s_waitcnt vmcnt(2)" ::: "memory");
                else              asm volatile("s_waitcnt vmcnt(0)" ::: "memory");
            }
            asm volatile("s_waitcnt lgkmcnt(0)" ::: "memory");
            __builtin_amdgcn_s_barrier();
            cur ^= 1;
        }

        float inv[4];
        #pragma unroll
        for (int j = 0; j < 4; ++j) inv[j] = 1.0f / l_run[j];
        const size_t bS = (size_t)b * 2048;
        #pragma unroll
        for (int db = 0; db < 4; ++db)
            #pragma unroll
            for (int j = 0; j < 4; ++j)
                attout[(bS + qbase + fc * 4 + j) * 1024 + h * 64 + db * 16 + fr] =
                    f2bf(acc_o[db][j] * inv[j]);
    }
}

// ---------------------------------------------------------------------------
extern "C" void kernel_launch(void* const* d_in, const int* in_sizes, int n_in,
                              void* d_out, int out_size, void* d_ws, size_t ws_size,
                              hipStream_t stream)
{
    const float* x    = (const float*)d_in[0];
    const float* Wq   = (const float*)d_in[1];
    const float* Wk   = (const float*)d_in[2];
    const float* Wv   = (const float*)d_in[3];
    const float* ln1g = (const float*)d_in[4];
    const float* ln1b = (const float*)d_in[5];
    const float* ln2g = (const float*)d_in[6];
    const float* ln2b = (const float*)d_in[7];
    const float* W1   = (const float*)d_in[8];
    const float* b1   = (const float*)d_in[9];
    const float* W2   = (const float*)d_in[10];
    const float* b2   = (const float*)d_in[11];

    char* ws = (char*)d_ws;
    u16*   wbf  = (u16*)(ws);                        // 5M bf16 = 10 MB
    u16*   xn   = (u16*)(ws + 10485760);             // 8M bf16 = 16 MB (reused as xt2)
    u16*   qkvb = (u16*)(ws + 27262976);             // 24M bf16 = 48 MB (reused as ffn hidden)
    u16*   attb = (u16*)(ws + 77594624);             // 8M bf16 = 16 MB
    float* xt   = (float*)(ws + 94371840);           // 8M fp32 = 32 MB

    cvt_w<<<1024, 256, 0, stream>>>(Wq, Wk, Wv, W1, W2, wbf);
    ln_kernel<false><<<8192, 256, 0, stream>>>(x, nullptr, ln1g, ln1b, nullptr, xn);
    gemm_bt<0><<<dim3(64, 24), 256, 0, stream>>>(xn, wbf, qkvb, nullptr, nullptr,
                                                 8192, 3072, 1024);
    attn_fwd<<<1024, 256, 0, stream>>>(qkvb, qkvb + 8388608, qkvb + 16777216, attb);
    ln_kernel<true><<<8192, 256, 0, stream>>>(x, attb, ln2g, ln2b, xt, xn);
    gemm_bt<1><<<dim3(64, 8), 256, 0, stream>>>(xn, wbf + (3 << 20), qkvb, b1, nullptr,
                                                8192, 1024, 1024);
    gemm_bt<2><<<dim3(64, 8), 256, 0, stream>>>(qkvb, wbf + (4 << 20), d_out, b2, xt,
                                                8192, 1024, 1024);
}